// Round 10
// baseline (6561.976 us; speedup 1.0000x reference)
//
#include <hip/hip_runtime.h>
#include <cstdint>
#include <cstddef>

#define TT 360
#define BFULL 512
#define GH 1024   /* 4*H */

typedef unsigned short u16;
typedef short bf16x8_t __attribute__((ext_vector_type(8)));
typedef short bf16x4_t __attribute__((ext_vector_type(4)));
typedef float f32x4_t  __attribute__((ext_vector_type(4)));

#define MFMA(A,B,C) __builtin_amdgcn_mfma_f32_16x16x32_bf16(A,B,C,0,0,0)

// raw barrier: drain LDS ops only (global loads/stores stay in flight)
#define LDS_BARRIER() do { \
  asm volatile("s_waitcnt lgkmcnt(0)" ::: "memory"); \
  __builtin_amdgcn_s_barrier(); \
} while (0)

__device__ __forceinline__ float bf2f(u16 u){
  union { unsigned u; float f; } v; v.u = ((unsigned)u) << 16; return v.f;
}
__device__ __forceinline__ u16 f2bf(float f){
  union { float f; unsigned u; } v; v.f = f;
  unsigned r = v.u + 0x7FFFu + ((v.u >> 16) & 1u);
  return (u16)(r >> 16);
}
__device__ __forceinline__ float sigm(float x){
  float e = __builtin_amdgcn_exp2f(-1.44269504089f * x);
  return __builtin_amdgcn_rcpf(1.f + e);
}
__device__ __forceinline__ float tanh_(float x){
  float e = __builtin_amdgcn_exp2f(-2.88539008178f * x);
  return 2.f * __builtin_amdgcn_rcpf(1.f + e) - 1.f;
}
__device__ __forceinline__ f32x4_t cvt4(bf16x4_t v){
  f32x4_t r;
#pragma unroll
  for (int i = 0; i < 4; ++i) r[i] = bf2f((u16)v[i]);
  return r;
}

// ---- device-coherent ops for cross-block exchange ----
__device__ __forceinline__ void st_u16_sc(void* p, u16 v){
  asm volatile("global_store_short %0, %1, off sc0 sc1" :: "v"(p), "v"(v) : "memory");
}
__device__ __forceinline__ void st_b128_sc(void* p, bf16x8_t v){
  asm volatile("global_store_dwordx4 %0, %1, off sc0 sc1" :: "v"(p), "v"(v) : "memory");
}
__device__ __forceinline__ void st_flag(int* p, int v){
  asm volatile("global_store_dword %0, %1, off sc0 sc1" :: "v"(p), "v"(v) : "memory");
}
__device__ __forceinline__ int ld_flag(const int* p){
  int v;
  asm volatile("global_load_dword %0, %1, off sc0 sc1\n\ts_waitcnt vmcnt(0)"
               : "=v"(v) : "v"(p) : "memory");
  return v;
}
__device__ __forceinline__ void ld2_b128_sc(const void* p0, const void* p1, f32x4_t* a, f32x4_t* b){
  asm volatile("global_load_dwordx4 %0, %2, off sc0 sc1\n\t"
               "global_load_dwordx4 %1, %3, off sc0 sc1\n\t"
               "s_waitcnt vmcnt(0)"
               : "=&v"(*a), "=&v"(*b) : "v"(p0), "v"(p1) : "memory");
}

// ---------------- small prep kernels ----------------

__global__ void k_cvt_pad(const float* src, u16* dst, int N, int srcK, int useK, int Np, int Kp){
  int i = blockIdx.x * blockDim.x + threadIdx.x;
  if (i >= Np * Kp) return;
  int n = i / Kp, k = i - n * Kp;
  float v = (n < N && k < useK) ? src[(size_t)n * srcK + k] : 0.f;
  dst[i] = f2bf(v);
}

// repack Whh [1024][256] f32 -> [ns(4)][g(4)][ct(4)][ks(8)][ln(64)][8] bf16
__global__ void k_repack(const float* src, u16* dst){
  int d = blockIdx.x * blockDim.x + threadIdx.x;   // 262144 total
  if (d >= 262144) return;
  int e  = d & 7;
  int ln = (d >> 3) & 63;
  int ks = (d >> 9) & 7;
  int ct = (d >> 12) & 3;
  int g  = (d >> 14) & 3;
  int ns = (d >> 16) & 3;
  int c = ns * 64 + ct * 16 + (ln & 15);
  int n = g * 256 + c;
  int k = ks * 32 + (ln >> 4) * 8 + e;
  dst[d] = f2bf(src[n * 256 + k]);
}

__global__ void k_bias_sum(const float* a, const float* b, float* o, int n){
  int i = blockIdx.x * blockDim.x + threadIdx.x;
  if (i < n) o[i] = a[i] + b[i];
}

__global__ void k_zero(int* p, int n){
  int i = blockIdx.x * blockDim.x + threadIdx.x;
  if (i < n) p[i] = 0;
}

// ---------------- projection GEMM (writes G in MFMA C-frag layout) ----------------
// G frag layout: [t][btile(Bg/16)][ntile(64)][lane(64)][4] bf16.

struct ProjArgs {
  const u16* A; const u16* W;
  const float* colbias;
  u16* G;
  int Akp, K, t0, rev, Bg, bgLog;
};

template<int BK>
__global__ __launch_bounds__(256) void k_proj(ProjArgs p){
  constexpr int SLOTS = BK / 8;
  constexpr int SM = SLOTS - 1;
  constexpr int LOG = (BK == 64) ? 3 : 2;
  __shared__ __align__(16) u16 lA[128 * BK];
  __shared__ __align__(16) u16 lW[128 * BK];
  const int tid = threadIdx.x, lane = tid & 63, wid = tid >> 6;
  const int wm = wid >> 1, wn = wid & 1;
  const int mBase = blockIdx.x * 128;
  const int nBase = blockIdx.y * 128;
  const int t_rel = mBase >> p.bgLog;
  const int bBase = mBase & (p.Bg - 1);
  const int t_glob = p.t0 + t_rel;
  const int t_src = p.rev ? (TT - 1 - t_glob) : t_glob;

  f32x4_t acc[4][4];
#pragma unroll
  for (int m = 0; m < 4; ++m)
#pragma unroll
    for (int n = 0; n < 4; ++n) acc[m][n] = (f32x4_t){0.f, 0.f, 0.f, 0.f};

  for (int k0 = 0; k0 < p.K; k0 += BK){
#pragma unroll
    for (int i = 0; i < (128 * SLOTS) / 256; ++i){
      int idx = i * 256 + tid;
      int row = idx >> LOG, sl = idx & SM;
      bf16x8_t va = *(const bf16x8_t*)(p.A + (size_t)((bBase + row) * TT + t_src) * p.Akp + k0 + sl * 8);
      *(bf16x8_t*)&lA[((row << LOG) + (sl ^ (row & SM))) * 8] = va;
      bf16x8_t vw = *(const bf16x8_t*)(p.W + (size_t)(nBase + row) * p.K + k0 + sl * 8);
      *(bf16x8_t*)&lW[((row << LOG) + (sl ^ (row & SM))) * 8] = vw;
    }
    __syncthreads();
#pragma unroll
    for (int kk = 0; kk < BK; kk += 32){
      bf16x8_t af[4], wf[4];
#pragma unroll
      for (int m = 0; m < 4; ++m){
        int row = wm * 64 + m * 16 + (lane & 15);
        int sl = ((kk >> 3) + (lane >> 4)) ^ (row & SM);
        af[m] = *(const bf16x8_t*)&lA[((row << LOG) + sl) * 8];
      }
#pragma unroll
      for (int n = 0; n < 4; ++n){
        int row = wn * 64 + n * 16 + (lane & 15);
        int sl = ((kk >> 3) + (lane >> 4)) ^ (row & SM);
        wf[n] = *(const bf16x8_t*)&lW[((row << LOG) + sl) * 8];
      }
#pragma unroll
      for (int m = 0; m < 4; ++m)
#pragma unroll
        for (int n = 0; n < 4; ++n)
          acc[m][n] = MFMA(af[m], wf[n], acc[m][n]);
    }
    __syncthreads();
  }

  const int btiles = p.Bg >> 4;
#pragma unroll
  for (int m = 0; m < 4; ++m){
    int btile = (bBase + wm * 64 + m * 16) >> 4;
#pragma unroll
    for (int n = 0; n < 4; ++n){
      int coltile = nBase + wn * 64 + n * 16;
      int col = coltile + (lane & 15);
      int ntile = coltile >> 4;
      float cb = p.colbias ? p.colbias[col] : 0.f;
      bf16x4_t outv;
#pragma unroll
      for (int q = 0; q < 4; ++q)
        outv[q] = (short)f2bf(acc[m][n][q] + cb);
      *(bf16x4_t*)(p.G + ((((size_t)t_rel * btiles + btile) * 64 + ntile) * 64 + lane) * 4) = outv;
    }
  }
}

// ---------------- unified LSTM recurrence: N-split, LDS-resident weights ----------------
// Block = 512 thr = 8 waves; cell group = (dir, 32 rows); 4 blocks/group (ns = col quarter).
// Whh slice (128 KB) LDS-resident. h exchanged per step via parity-double-buffered
// device-coherent global buffer + monotonic flags. Publish path: activations -> LDS tile
// hS[32][64] -> 256 coalesced 16-B sc stores (swizzle applied when reading hS), so the
// pre-flag drain waits on full-line writes only. Y written from hS after the flag.
// MODE: 0=enc-l0 (x-fused), 1=dec-l0 (x-fused+zconst), 2=enc-l1 (G), 3=dec-l1 (G+outproj)

struct RecArgs {
  const u16* Wr0; const u16* Wr1;       // repacked Whh per dir
  int* flg0; int* flg1;                 // flag base per dir (bt*4 added in kernel)
  u16* hX0; u16* hX1;                   // exchange base per dir (bt*16384 u16 added)
  const u16* G0; const u16* G1; int btilesG;
  const float* x; const int* labels; const float* emb; int gb0;
  const float* cb0; const float* cb1;   // enc-l0 bias per dir
  const u16* Wx0; const u16* Wx1;       // [1024][32] input weights per dir (XIN)
  const u16* zcF;                       // dec-l0 frag-layout const (pre-offset)
  const u16* hI0; const u16* hI1;       // initial h or null=zeros
  const float* cI0; const float* cI1;   // initial c or null=zeros
  float* cS0; float* cS1;               // c writeback or null
  u16* hW0; u16* hW1;                   // final h writeback or null
  u16* Y; int ycols; int yoff0; int yoff1;
  const u16* Wo; const float* bo; float* outp;
  int t0, t1, nbt;
};

template<int MODE>
__global__ __launch_bounds__(512, 1) void k_rec(RecArgs a){
  constexpr bool XIN  = (MODE <= 1);
  constexpr bool DEC  = (MODE == 1);
  constexpr bool GIN  = (MODE >= 2);
  constexpr bool OUTP = (MODE == 3);

  __shared__ __align__(16) u16 Wlds[65536];   // 128 KB
  __shared__ __align__(16) u16 hlds[8192];    // 16 KB
  __shared__ __align__(16) u16 hS[2048];      // 4 KB   [32 rows][64 cols] own quarter
  __shared__ __align__(16) u16 xT[1024];      // 2 KB

  const int bx = blockIdx.x;
  const int ns = bx & 3;
  const int gid = bx >> 2;
  const int dir = gid / a.nbt;
  const int bt = gid - dir * a.nbt;
  const int bb = bt * 32;
  const int tid = threadIdx.x;
  const int lane = tid & 63, w = tid >> 6;
  const int l15 = lane & 15, lhi = lane >> 4;
  const int mt = w >> 2, ct = w & 3;
  const int colb = ns * 64 + ct * 16 + l15;
  const int cq = ct * 16 + l15;              // col within own quarter

  const u16* Wsrc = (dir ? a.Wr1 : a.Wr0) + (size_t)ns * 65536;
  int* flg = (dir ? a.flg1 : a.flg0) + bt * 4;
  u16* hXg = (dir ? a.hX1 : a.hX0) + (size_t)bt * 16384;
  const int yoff = dir ? a.yoff1 : a.yoff0;

  // ---- stage weight slab 128 KB -> LDS ----
#pragma unroll
  for (int i = 0; i < 16; ++i){
    int idx = i * 512 + tid;
    *(f32x4_t*)((char*)Wlds + (size_t)idx * 16) = *(const f32x4_t*)((const char*)Wsrc + (size_t)idx * 16);
  }

  // ---- c init ----
  float cfr[4];
  {
    const float* cp = dir ? a.cI1 : a.cI0;
#pragma unroll
    for (int q = 0; q < 4; ++q)
      cfr[q] = cp ? cp[(size_t)(bb + mt * 16 + lhi * 4 + q) * 256 + colb] : 0.f;
  }

  // ---- per-mode constants ----
  float bias4[4];
  f32x4_t zcv[4];
  bf16x8_t wfx[4];
  if (XIN && !DEC){
    const float* cb = dir ? a.cb1 : a.cb0;
#pragma unroll
    for (int g = 0; g < 4; ++g) bias4[g] = cb[g * 256 + colb];
  }
  if (DEC){
#pragma unroll
    for (int g = 0; g < 4; ++g){
      int ntile = g * 16 + ns * 4 + ct;
      bf16x4_t zv = *(const bf16x4_t*)(a.zcF + ((((size_t)((bb >> 4) + mt)) * 64 + ntile) * 64 + lane) * 4);
      zcv[g] = cvt4(zv);
    }
  }
  if (XIN){
    const u16* Wx = dir ? a.Wx1 : a.Wx0;
#pragma unroll
    for (int g = 0; g < 4; ++g)
      wfx[g] = *(const bf16x8_t*)(Wx + (size_t)(g * 256 + colb) * 32 + lhi * 8);
  }
  bf16x8_t wo8[8];
  float bo = 0.f;
  if (OUTP && ns == 0 && w < 2){
#pragma unroll
    for (int ks = 0; ks < 8; ++ks)
      wo8[ks] = *(const bf16x8_t*)(a.Wo + (size_t)l15 * 256 + ks * 32 + lhi * 8);
    if (l15 < 12) bo = a.bo[l15];
  }

  // ---- xT init ----
  if (XIN){
    int row = tid >> 4, c16 = tid & 15;
    int gr = a.gb0 + bb + row;
    u16 vA = 0, vB = 0;
    if (!DEC){
      int lb = a.labels[gr];
      if (c16 >= 12) vA = f2bf(a.emb[lb * 8 + (c16 - 12)]);
      if (c16 < 4)   vB = f2bf(a.emb[lb * 8 + 4 + c16]);
    }
    u16 x0 = 0;
    if (!DEC && c16 < 12){
      int t0src = dir ? (TT - 1) : 0;
      x0 = f2bf(a.x[((size_t)gr * TT + t0src) * 12 + c16]);
    }
    xT[row * 32 + c16] = (c16 < 12) ? x0 : vA;
    xT[row * 32 + 16 + c16] = vB;
  }

  // ---- precomputed offsets ----
  unsigned dsA[8];
#pragma unroll
  for (int ks = 0; ks < 8; ++ks)
    dsA[ks] = (unsigned)((((mt * 16 + l15) << 5) + (((ks << 2) + lhi) ^ (l15 & 7))) * 16);
  unsigned wrO[4];
#pragma unroll
  for (int q = 0; q < 4; ++q){
    int row = mt * 16 + lhi * 4 + q;
    wrO[q] = (unsigned)((row << 9) + (((colb >> 3) ^ (row & 7)) << 4) + ((colb & 7) << 1));
  }
  // publish / Y constants (first 256 threads act)
  const int prow = tid >> 3, pj = tid & 7;
  const unsigned pubO = (unsigned)(prow * 512 + ns * 128 + pj * 16);
  const unsigned pubS = (unsigned)((prow * 64 + (pj ^ (prow & 7)) * 8) * 2);
  // G offsets + prefetch registers (GIN)
  const char* Gc = GIN ? (const char*)(dir ? a.G1 : a.G0) : nullptr;
  unsigned gOff[4];
  const unsigned gstep = (unsigned)a.btilesG * 32768u;
  bf16x4_t gvP[4];
  if (GIN){
#pragma unroll
    for (int g = 0; g < 4; ++g){
      int ntile = g * 16 + ns * 4 + ct;
      gOff[g] = (unsigned)((((bb >> 4) + mt) * 64 + ntile) * 512 + lane * 8);
    }
#pragma unroll
    for (int g = 0; g < 4; ++g)
      gvP[g] = *(const bf16x4_t*)(Gc + gOff[g]);
  }

  // ---- initial publish h(0) (t0==0 only) ----
  if (a.t0 == 0){
    const u16* hp = dir ? a.hI1 : a.hI0;
#pragma unroll
    for (int q = 0; q < 4; ++q){
      u16 hv = hp ? hp[(size_t)(bb + mt * 16 + lhi * 4 + q) * 256 + colb] : (u16)0;
      st_u16_sc((char*)hXg + wrO[q], hv);
    }
  }
  __syncthreads();                                  // drains W-stage + sc stores
  if (tid == 0 && a.t0 == 0) st_flag(flg + ns, 1);

  auto spin_to = [&](int target){
    if (w == 0){
      while (true){
        int f = (lane < 4) ? ld_flag(flg + lane) : target;
        if (__all(f >= target)) break;
        __builtin_amdgcn_s_sleep(2);
      }
    }
    __syncthreads();
  };
  auto stage_h = [&](int par){
    const char* src = (const char*)hXg + par * 16384;
    int o0 = (w * 2) * 1024 + lane * 16;
    f32x4_t v0, v1;
    ld2_b128_sc(src + o0, src + o0 + 1024, &v0, &v1);
    *(f32x4_t*)((char*)hlds + o0) = v0;
    *(f32x4_t*)((char*)hlds + o0 + 1024) = v1;
  };

  spin_to(a.t0 + 1);
  stage_h(a.t0 & 1);
  __syncthreads();

  for (int t = a.t0; t < a.t1; ++t){
    // dec-l1: out-projection of h(t) -> out[t-1]
    if (OUTP && ns == 0 && w < 2 && t > 0){
      f32x4_t oa = (f32x4_t){0.f, 0.f, 0.f, 0.f};
#pragma unroll
      for (int ks = 0; ks < 8; ++ks){
        bf16x8_t af = *(const bf16x8_t*)((char*)hlds + w * 8192 + dsA[ks]);
        oa = MFMA(af, wo8[ks], oa);
      }
      if (l15 < 12){
#pragma unroll
        for (int q = 0; q < 4; ++q)
          a.outp[((size_t)(bb + w * 16 + lhi * 4 + q) * TT + (t - 1)) * 12 + l15] = oa[q] + bo;
      }
    }
    // gate accumulation
    f32x4_t acc[4];
    if (GIN){
#pragma unroll
      for (int g = 0; g < 4; ++g) acc[g] = cvt4(gvP[g]);
    } else if (DEC){
#pragma unroll
      for (int g = 0; g < 4; ++g) acc[g] = zcv[g];
    } else {
#pragma unroll
      for (int g = 0; g < 4; ++g) acc[g] = (f32x4_t){bias4[g], bias4[g], bias4[g], bias4[g]};
    }
    if (XIN){
      bf16x8_t ax = *(const bf16x8_t*)((char*)xT + (mt * 16 + l15) * 64 + lhi * 16);
#pragma unroll
      for (int g = 0; g < 4; ++g) acc[g] = MFMA(ax, wfx[g], acc[g]);
    }
#pragma unroll
    for (int ks = 0; ks < 8; ++ks){
      bf16x8_t af = *(const bf16x8_t*)((char*)hlds + dsA[ks]);
#pragma unroll
      for (int g = 0; g < 4; ++g){
        bf16x8_t bf = *(const bf16x8_t*)((char*)Wlds + ((g * 4 + ct) * 8 + ks) * 1024 + lane * 16);
        acc[g] = MFMA(af, bf, acc[g]);
      }
    }
    // activations -> hS (LDS)
#pragma unroll
    for (int q = 0; q < 4; ++q){
      float iv = sigm(acc[0][q]);
      float fv = sigm(acc[1][q]);
      float gv = tanh_(acc[2][q]);
      float ov = sigm(acc[3][q]);
      float c = fv * cfr[q] + iv * gv;
      cfr[q] = c;
      hS[(mt * 16 + lhi * 4 + q) * 64 + cq] = f2bf(ov * tanh_(c));
    }
    LDS_BARRIER();                                 // hS complete
    // coalesced publish: 256 x 16B sc stores (swizzled image)
    const int par = (t + 1) & 1;
    if (tid < 256){
      bf16x8_t v = *(const bf16x8_t*)((char*)hS + pubS);
      st_b128_sc((char*)hXg + par * 16384 + pubO, v);
    }
    asm volatile("s_waitcnt vmcnt(0)" ::: "memory");
    __builtin_amdgcn_s_barrier();                  // all publish stores drained
    if (tid == 0) st_flag(flg + ns, t + 2);
    // Y stores AFTER flag (coalesced 16B rows from hS)
    if (XIN && tid < 256){
      const int ty = (MODE == 0 && dir) ? (TT - 1 - t) : t;
      bf16x8_t v = *(const bf16x8_t*)&hS[prow * 64 + pj * 8];
      *(bf16x8_t*)(a.Y + ((size_t)(bb + prow) * TT + ty) * a.ycols + yoff + ns * 64 + pj * 8) = v;
    }
    // G prefetch for t+1 (rides the handshake)
    if (GIN){
#pragma unroll
      for (int g = 0; g < 4; ++g) gOff[g] += gstep;
      if (t + 1 < a.t1){
#pragma unroll
        for (int g = 0; g < 4; ++g)
          gvP[g] = *(const bf16x4_t*)(Gc + gOff[g]);
      }
    }
    spin_to(t + 2);
    stage_h(par);
    if (XIN && (t + 1) < a.t1){
      if (tid < 128 && (tid & 3) < 3){
        int row = tid >> 2, xq = tid & 3;
        int tsrc = DEC ? t : (dir ? (TT - 2 - t) : (t + 1));
        f32x4_t xv = *(const f32x4_t*)(a.x + ((size_t)(a.gb0 + bb + row) * TT + tsrc) * 12 + xq * 4);
        bf16x4_t xb;
#pragma unroll
        for (int e = 0; e < 4; ++e) xb[e] = (short)f2bf(xv[e]);
        *(bf16x4_t*)((char*)xT + row * 64 + xq * 8) = xb;
      }
    }
    LDS_BARRIER();                                 // hlds/xT ready
  }

  // epilogue: dec-l1 projects h(t1) -> out[t1-1]
  if (OUTP && ns == 0 && w < 2){
    f32x4_t oa = (f32x4_t){0.f, 0.f, 0.f, 0.f};
#pragma unroll
    for (int ks = 0; ks < 8; ++ks){
      bf16x8_t af = *(const bf16x8_t*)((char*)hlds + w * 8192 + dsA[ks]);
      oa = MFMA(af, wo8[ks], oa);
    }
    if (l15 < 12){
#pragma unroll
      for (int q = 0; q < 4; ++q)
        a.outp[((size_t)(bb + w * 16 + lhi * 4 + q) * TT + (a.t1 - 1)) * 12 + l15] = oa[q] + bo;
    }
  }
  // state writeback (hlds holds staged h(t1))
  {
    float* cs = dir ? a.cS1 : a.cS0;
    if (cs){
#pragma unroll
      for (int q = 0; q < 4; ++q)
        cs[(size_t)(bb + mt * 16 + lhi * 4 + q) * 256 + colb] = cfr[q];
    }
    u16* hw = dir ? a.hW1 : a.hW0;
    if (hw){
#pragma unroll
      for (int q = 0; q < 4; ++q){
        u16 hv = *(u16*)((char*)hlds + wrO[q]);
        hw[(size_t)(bb + mt * 16 + lhi * 4 + q) * 256 + colb] = hv;
      }
    }
  }
}

// ---------------- mid kernels (full batch, small) ----------------

__global__ void k_mulv(const u16* sH0, const u16* sH1,
                       const float* Wmu, const float* bmu,
                       const float* Wlv, const float* blv, float* mulv){
  int i = blockIdx.x * blockDim.x + threadIdx.x;
  if (i >= BFULL * 128) return;
  int b = i >> 7, j = i & 127;
  const float* W = (j < 64) ? (Wmu + (size_t)j * 512) : (Wlv + (size_t)(j - 64) * 512);
  float s = (j < 64) ? bmu[j] : blv[j - 64];
  for (int k = 0; k < 256; ++k) s += bf2f(sH0[(size_t)b * 256 + k]) * W[k];
  for (int k = 0; k < 256; ++k) s += bf2f(sH1[(size_t)b * 256 + k]) * W[256 + k];
  mulv[i] = s;
}

__global__ void k_sample(const float* mulv, const float* eps, const int* labels, const float* emb,
                         float* out_mu, float* out_lv, float* out_z, float* zcf){
  int i = blockIdx.x * blockDim.x + threadIdx.x;
  if (i >= BFULL * 128) return;
  int b = i >> 7, j = i & 127;
  if (j < 64){
    float mu = mulv[b * 128 + j];
    float lv = mulv[b * 128 + 64 + j];
    float z = mu + eps[b * 64 + j] * __expf(0.5f * lv);
    out_mu[b * 64 + j] = mu;
    out_lv[b * 64 + j] = lv;
    out_z[b * 64 + j] = z;
    zcf[i] = z;
  } else if (j < 72){
    zcf[i] = emb[labels[b] * 8 + (j - 64)];
  } else {
    zcf[i] = 0.f;
  }
}

__global__ void k_hc(const float* zcf, const float* Whid, const float* bhid,
                     const float* Wcell, const float* bcell, float* HC){
  int i = blockIdx.x * blockDim.x + threadIdx.x;
  if (i >= BFULL * 1024) return;
  int b = i >> 10, n = i & 1023;
  const float* W; float s;
  if (n < 512){ W = Whid + (size_t)n * 72; s = bhid[n]; }
  else        { W = Wcell + (size_t)(n - 512) * 72; s = bcell[n - 512]; }
  for (int k = 0; k < 72; ++k) s += zcf[b * 128 + k] * W[k];
  HC[i] = s;
}

__global__ void k_zconst(const float* zcf, const float* dWih0,
                         const float* dbih0, const float* dbhh0, float* zconst){
  int i = blockIdx.x * blockDim.x + threadIdx.x;
  if (i >= BFULL * 1024) return;
  int b = i >> 10, n = i & 1023;
  float s = dbih0[n] + dbhh0[n];
  const float* W = dWih0 + (size_t)n * 84 + 12;
  for (int k = 0; k < 72; ++k) s += zcf[b * 128 + k] * W[k];
  zconst[i] = s;
}

__global__ void k_zfrag(const float* zconst, u16* zcF){
  int i = blockIdx.x * blockDim.x + threadIdx.x;
  if (i >= BFULL * GH) return;
  int q = i & 3, ln = (i >> 2) & 63, nt = (i >> 8) & 63, bt = i >> 14;
  int r = bt * 16 + (ln >> 4) * 4 + q;
  int col = nt * 16 + (ln & 15);
  zcF[i] = f2bf(zconst[(size_t)r * GH + col]);
}

// faithful torch .view(NL, B, H) on [B, NL*H]
__global__ void k_dec_init(const float* HC, u16* h0, float* c0, u16* h1, float* c1){
  int i = blockIdx.x * blockDim.x + threadIdx.x;
  if (i >= BFULL * 256) return;
  int b = i >> 8, h = i & 255;
  int col = (b & 1) * 256 + h;
  int r0 = b >> 1;
  int r1 = 256 + (b >> 1);
  h0[i] = f2bf(HC[(size_t)r0 * 1024 + col]);
  c0[i] =      HC[(size_t)r0 * 1024 + 512 + col];
  h1[i] = f2bf(HC[(size_t)r1 * 1024 + col]);
  c1[i] =      HC[(size_t)r1 * 1024 + 512 + col];
}

// ---------------- host ----------------

static inline size_t alignup(size_t x){ return (x + 255) & ~(size_t)255; }
static inline int ilog2(int x){ return 31 - __builtin_clz((unsigned)x); }

extern "C" void kernel_launch(void* const* d_in, const int* in_sizes, int n_in,
                              void* d_out, int out_size, void* d_ws, size_t ws_size,
                              hipStream_t stream){
  const float* x      = (const float*)d_in[0];
  const int*   labels = (const int*)  d_in[1];
  const float* eps    = (const float*)d_in[2];
  const float* emb    = (const float*)d_in[3];
  const float* Wih0f = (const float*)d_in[4],  *Whh0f = (const float*)d_in[5];
  const float* bih0f = (const float*)d_in[6],  *bhh0f = (const float*)d_in[7];
  const float* Wih0b = (const float*)d_in[8],  *Whh0b = (const float*)d_in[9];
  const float* bih0b = (const float*)d_in[10], *bhh0b = (const float*)d_in[11];
  const float* Wih1f = (const float*)d_in[12], *Whh1f = (const float*)d_in[13];
  const float* bih1f = (const float*)d_in[14], *bhh1f = (const float*)d_in[15];
  const float* Wih1b = (const float*)d_in[16], *Whh1b = (const float*)d_in[17];
  const float* bih1b = (const float*)d_in[18], *bhh1b = (const float*)d_in[19];
  const float* Wmu = (const float*)d_in[20], *bmu = (const float*)d_in[21];
  const float* Wlv = (const float*)d_in[22], *blv = (const float*)d_in[23];
  const float* Whid = (const float*)d_in[24], *bhid = (const float*)d_in[25];
  const float* Wcell = (const float*)d_in[26], *bcell = (const float*)d_in[27];
  const float* dWih0 = (const float*)d_in[28], *dWhh0 = (const float*)d_in[29];
  const float* dbih0 = (const float*)d_in[30], *dbhh0 = (const float*)d_in[31];
  const float* dWih1 = (const float*)d_in[32], *dWhh1 = (const float*)d_in[33];
  const float* dbih1 = (const float*)d_in[34], *dbhh1 = (const float*)d_in[35];
  const float* Wout = (const float*)d_in[36], *bout = (const float*)d_in[37];

  float* out = (float*)d_out;
  float* out_mu = out + (size_t)BFULL * TT * 12;
  float* out_lv = out_mu + (size_t)BFULL * 64;
  float* out_z  = out_lv + (size_t)BFULL * 64;

  // ---- fixed ws allocations ----
  char* ws = (char*)d_ws; size_t off = 0;
  auto alloc = [&](size_t bytes)->char*{ char* p = ws + off; off += alignup(bytes); return p; };

  u16* W0f_b  = (u16*)alloc(1024 * 32 * 2);
  u16* W0b_b  = (u16*)alloc(1024 * 32 * 2);
  u16* dWx_b  = (u16*)alloc(1024 * 32 * 2);
  u16* Wo_b   = (u16*)alloc(16 * 256 * 2);
  u16* Whh0f_r = (u16*)alloc((size_t)1024 * 256 * 2);
  u16* Whh0b_r = (u16*)alloc((size_t)1024 * 256 * 2);
  u16* Whh1f_r = (u16*)alloc((size_t)1024 * 256 * 2);
  u16* Whh1b_r = (u16*)alloc((size_t)1024 * 256 * 2);
  u16* dWhh0_r = (u16*)alloc((size_t)1024 * 256 * 2);
  u16* dWhh1_r = (u16*)alloc((size_t)1024 * 256 * 2);
  u16* dWih1_b = (u16*)alloc((size_t)1024 * 256 * 2);
  u16* Wih1f_b = (u16*)alloc((size_t)1024 * 512 * 2);
  u16* Wih1b_b = (u16*)alloc((size_t)1024 * 512 * 2);
  float* b0f = (float*)alloc(1024 * 4);
  float* b0b = (float*)alloc(1024 * 4);
  float* b1f = (float*)alloc(1024 * 4);
  float* b1b = (float*)alloc(1024 * 4);
  float* db1 = (float*)alloc(1024 * 4);
  u16*  sHe1 = (u16*)alloc((size_t)2 * BFULL * 256 * 2);
  float* sCe1 = (float*)alloc((size_t)2 * BFULL * 256 * 4);
  u16*  dh0 = (u16*)alloc((size_t)BFULL * 256 * 2);
  float* dc0 = (float*)alloc((size_t)BFULL * 256 * 4);
  u16*  dh1 = (u16*)alloc((size_t)BFULL * 256 * 2);
  float* dc1 = (float*)alloc((size_t)BFULL * 256 * 4);
  float* mulv = (float*)alloc((size_t)BFULL * 128 * 4);
  float* zcf  = (float*)alloc((size_t)BFULL * 128 * 4);
  float* HC   = (float*)alloc((size_t)BFULL * 1024 * 4);
  float* zconst = (float*)alloc((size_t)BFULL * 1024 * 4);
  u16*  zcF   = (u16*)alloc((size_t)BFULL * 1024 * 2);
  int*  flagsA = (int*)alloc(512 * 4);                         // [layer4][dir2][btGlobal16][ns4]
  u16*  hXA    = (u16*)alloc((size_t)2 * 16 * 16384 * 2);      // [dir2][btGlobal16][2par][8192]

  // ---- scheme chooser: batch-group eb and G T-chunk Tc (prefer full-T) ----
  size_t rem = (ws_size > off + (1 << 20)) ? ws_size - off - (1 << 20) : 0;
  int eb = 128, Tc = 2;
  {
    const int sch[][2] = {
      {512,360},{512,120},{512,40},{512,24},{512,12},{512,8},
      {256,360},{256,120},{256,40},{256,12},{256,8},
      {128,360},{128,40},{128,8},{128,2}};
    for (int i = 0; i < (int)(sizeof(sch)/sizeof(sch[0])); ++i){
      size_t need = alignup((size_t)sch[i][0] * TT * 512 * 2)
                  + 2 * alignup((size_t)sch[i][1] * sch[i][0] * GH * 2);
      if (need <= rem){ eb = sch[i][0]; Tc = sch[i][1]; break; }
    }
  }
  const int ebLog = ilog2(eb);
  const int nGroups = BFULL / eb;
  const int nbt = eb / 32;

  u16* y0 = (u16*)alloc((size_t)eb * TT * 512 * 2);   // enc y (512 cols); decoder aliases 256-col y0d
  u16* Gf = (u16*)alloc((size_t)Tc * eb * GH * 2);
  u16* Gb = (u16*)alloc((size_t)Tc * eb * GH * 2);
  u16* y0d = y0;

  auto cvt = [&](const float* src, u16* dst, int N, int srcK, int useK, int Np, int Kp){
    int tot = Np * Kp;
    k_cvt_pad<<<(tot + 255) / 256, 256, 0, stream>>>(src, dst, N, srcK, useK, Np, Kp);
  };
  auto repack = [&](const float* src, u16* dst){
    k_repack<<<1024, 256, 0, stream>>>(src, dst);
  };
  auto bsum = [&](const float* a, const float* b, float* o){
    k_bias_sum<<<4, 256, 0, stream>>>(a, b, o, 1024);
  };
  auto proj = [&](const u16* A, int Akp, int K, const u16* W, const float* cbp,
                  u16* G, int t0, int tc, int rev){
    ProjArgs pa; pa.A = A; pa.W = W; pa.colbias = cbp; pa.G = G;
    pa.Akp = Akp; pa.K = K; pa.t0 = t0; pa.rev = rev; pa.Bg = eb; pa.bgLog = ebLog;
    dim3 grid(tc * (eb / 128), 8);
    k_proj<64><<<grid, 256, 0, stream>>>(pa);
  };
  auto flgbase = [&](int layer, int d, int gb0){ return flagsA + ((layer * 2 + d) * 16 + (gb0 >> 5)) * 4; };
  auto hxbase  = [&](int d, int gb0){ return hXA + ((size_t)d * 16 + (gb0 >> 5)) * 16384; };

  // ---- flags reset + weight prep ----
  k_zero<<<2, 256, 0, stream>>>(flagsA, 512);
  cvt(Wih0f, W0f_b, 1024, 20, 20, 1024, 32);
  cvt(Wih0b, W0b_b, 1024, 20, 20, 1024, 32);
  cvt(dWih0, dWx_b, 1024, 84, 12, 1024, 32);
  cvt(Wout,  Wo_b,  12, 256, 256, 16, 256);
  repack(Whh0f, Whh0f_r);
  repack(Whh0b, Whh0b_r);
  repack(Whh1f, Whh1f_r);
  repack(Whh1b, Whh1b_r);
  repack(dWhh0, dWhh0_r);
  repack(dWhh1, dWhh1_r);
  cvt(dWih1, dWih1_b, 1024, 256, 256, 1024, 256);
  cvt(Wih1f, Wih1f_b, 1024, 512, 512, 1024, 512);
  cvt(Wih1b, Wih1b_b, 1024, 512, 512, 1024, 512);
  bsum(bih0f, bhh0f, b0f);
  bsum(bih0b, bhh0b, b0b);
  bsum(bih1f, bhh1f, b1f);
  bsum(bih1b, bhh1b, b1b);
  bsum(dbih1, dbhh1, db1);

  // ---- encoder ----
  for (int g = 0; g < nGroups; ++g){
    int gb0 = g * eb;
    {
      RecArgs ra = {};
      ra.Wr0 = Whh0f_r; ra.Wr1 = Whh0b_r;
      ra.flg0 = flgbase(0, 0, gb0); ra.flg1 = flgbase(0, 1, gb0);
      ra.hX0 = hxbase(0, gb0); ra.hX1 = hxbase(1, gb0);
      ra.x = x; ra.labels = labels; ra.emb = emb; ra.gb0 = gb0;
      ra.cb0 = b0f; ra.cb1 = b0b;
      ra.Wx0 = W0f_b; ra.Wx1 = W0b_b;
      ra.Y = y0; ra.ycols = 512; ra.yoff0 = 0; ra.yoff1 = 256;
      ra.t0 = 0; ra.t1 = TT; ra.nbt = nbt;
      k_rec<0><<<2 * nbt * 4, 512, 0, stream>>>(ra);
    }
    for (int t0 = 0; t0 < TT; t0 += Tc){
      int t1 = (t0 + Tc < TT) ? t0 + Tc : TT; int tc = t1 - t0;
      proj(y0, 512, 512, Wih1f_b, b1f, Gf, t0, tc, 0);
      proj(y0, 512, 512, Wih1b_b, b1b, Gb, t0, tc, 1);
      RecArgs ra = {};
      ra.Wr0 = Whh1f_r; ra.Wr1 = Whh1b_r;
      ra.flg0 = flgbase(1, 0, gb0); ra.flg1 = flgbase(1, 1, gb0);
      ra.hX0 = hxbase(0, gb0); ra.hX1 = hxbase(1, gb0);
      ra.G0 = Gf; ra.G1 = Gb; ra.btilesG = eb >> 4;
      ra.cI0 = t0 ? (sCe1 + (size_t)gb0 * 256) : nullptr;
      ra.cI1 = t0 ? (sCe1 + (size_t)BFULL * 256 + (size_t)gb0 * 256) : nullptr;
      ra.cS0 = sCe1 + (size_t)gb0 * 256;
      ra.cS1 = sCe1 + (size_t)BFULL * 256 + (size_t)gb0 * 256;
      ra.hW0 = sHe1 + (size_t)gb0 * 256;
      ra.hW1 = sHe1 + (size_t)BFULL * 256 + (size_t)gb0 * 256;
      ra.t0 = t0; ra.t1 = t1; ra.nbt = nbt;
      k_rec<2><<<2 * nbt * 4, 512, 0, stream>>>(ra);
    }
  }

  // ---- VAE head + decoder init ----
  k_mulv<<<(BFULL * 128) / 256, 256, 0, stream>>>(sHe1, sHe1 + (size_t)BFULL * 256,
                                                  Wmu, bmu, Wlv, blv, mulv);
  k_sample<<<(BFULL * 128) / 256, 256, 0, stream>>>(mulv, eps, labels, emb,
                                                    out_mu, out_lv, out_z, zcf);
  k_hc<<<(BFULL * 1024) / 256, 256, 0, stream>>>(zcf, Whid, bhid, Wcell, bcell, HC);
  k_zconst<<<(BFULL * 1024) / 256, 256, 0, stream>>>(zcf, dWih0, dbih0, dbhh0, zconst);
  k_zfrag<<<(BFULL * GH) / 256, 256, 0, stream>>>(zconst, zcF);
  k_dec_init<<<(BFULL * 256) / 256, 256, 0, stream>>>(HC, dh0, dc0, dh1, dc1);

  // ---- decoder ----
  for (int g = 0; g < nGroups; ++g){
    int gb0 = g * eb;
    {
      RecArgs ra = {};
      ra.Wr0 = dWhh0_r; ra.Wr1 = dWhh0_r;
      ra.flg0 = flgbase(2, 0, gb0); ra.flg1 = flgbase(2, 0, gb0);
      ra.hX0 = hxbase(0, gb0); ra.hX1 = hxbase(0, gb0);
      ra.x = x; ra.gb0 = gb0;
      ra.zcF = zcF + ((size_t)(gb0 >> 4)) * 16384;
      ra.Wx0 = dWx_b; ra.Wx1 = dWx_b;
      ra.hI0 = dh0 + (size_t)gb0 * 256;
      ra.cI0 = dc0 + (size_t)gb0 * 256;
      ra.Y = y0d; ra.ycols = 256; ra.yoff0 = 0; ra.yoff1 = 0;
      ra.t0 = 0; ra.t1 = TT; ra.nbt = nbt;
      k_rec<1><<<nbt * 4, 512, 0, stream>>>(ra);
    }
    for (int t0 = 0; t0 < TT; t0 += Tc){
      int t1 = (t0 + Tc < TT) ? t0 + Tc : TT; int tc = t1 - t0;
      proj(y0d, 256, 256, dWih1_b, db1, Gf, t0, tc, 0);
      RecArgs ra = {};
      ra.Wr0 = dWhh1_r; ra.Wr1 = dWhh1_r;
      ra.flg0 = flgbase(3, 0, gb0); ra.flg1 = flgbase(3, 0, gb0);
      ra.hX0 = hxbase(0, gb0); ra.hX1 = hxbase(0, gb0);
      ra.G0 = Gf; ra.G1 = Gf; ra.btilesG = eb >> 4;
      ra.hI0 = dh1 + (size_t)gb0 * 256;
      ra.cI0 = t0 ? (sCe1 + (size_t)gb0 * 256) : (dc1 + (size_t)gb0 * 256);
      ra.cS0 = sCe1 + (size_t)gb0 * 256;
      ra.Wo = Wo_b; ra.bo = bout;
      ra.outp = out + (size_t)gb0 * TT * 12;
      ra.t0 = t0; ra.t1 = t1; ra.nbt = nbt;
      k_rec<3><<<nbt * 4, 512, 0, stream>>>(ra);
    }
  }
}

// Round 11
// 4935.846 us; speedup vs baseline: 1.3295x; 1.3295x over previous
//
#include <hip/hip_runtime.h>
#include <cstdint>
#include <cstddef>

#define TT 360
#define BFULL 512
#define GH 1024   /* 4*H */

typedef unsigned short u16;
typedef short bf16x8_t __attribute__((ext_vector_type(8)));
typedef short bf16x4_t __attribute__((ext_vector_type(4)));
typedef float f32x4_t  __attribute__((ext_vector_type(4)));

#define MFMA(A,B,C) __builtin_amdgcn_mfma_f32_16x16x32_bf16(A,B,C,0,0,0)

__device__ __forceinline__ float bf2f(u16 u){
  union { unsigned u; float f; } v; v.u = ((unsigned)u) << 16; return v.f;
}
__device__ __forceinline__ u16 f2bf(float f){
  union { float f; unsigned u; } v; v.f = f;
  unsigned r = v.u + 0x7FFFu + ((v.u >> 16) & 1u);
  return (u16)(r >> 16);
}
__device__ __forceinline__ float sigm(float x){
  float e = __builtin_amdgcn_exp2f(-1.44269504089f * x);
  return __builtin_amdgcn_rcpf(1.f + e);
}
__device__ __forceinline__ float tanh_(float x){
  float e = __builtin_amdgcn_exp2f(-2.88539008178f * x);
  return 2.f * __builtin_amdgcn_rcpf(1.f + e) - 1.f;
}
__device__ __forceinline__ f32x4_t cvt4(bf16x4_t v){
  f32x4_t r;
#pragma unroll
  for (int i = 0; i < 4; ++i) r[i] = bf2f((u16)v[i]);
  return r;
}

// ---- device-coherent ops for cross-block exchange ----
__device__ __forceinline__ void st_u16_sc(void* p, u16 v){
  asm volatile("global_store_short %0, %1, off sc0 sc1" :: "v"(p), "v"(v) : "memory");
}
__device__ __forceinline__ void st_flag(int* p, int v){
  asm volatile("global_store_dword %0, %1, off sc0 sc1" :: "v"(p), "v"(v) : "memory");
}
__device__ __forceinline__ int ld_flag(const int* p){
  int v;
  asm volatile("global_load_dword %0, %1, off sc0 sc1\n\ts_waitcnt vmcnt(0)"
               : "=v"(v) : "v"(p) : "memory");
  return v;
}
__device__ __forceinline__ void ld2_b128_sc(const void* p0, const void* p1, f32x4_t* a, f32x4_t* b){
  asm volatile("global_load_dwordx4 %0, %2, off sc0 sc1\n\t"
               "global_load_dwordx4 %1, %3, off sc0 sc1\n\t"
               "s_waitcnt vmcnt(0)"
               : "=&v"(*a), "=&v"(*b) : "v"(p0), "v"(p1) : "memory");
}
__device__ __forceinline__ void ld4_b128_sc(const void* p0, const void* p1, const void* p2, const void* p3,
                                            f32x4_t* a, f32x4_t* b, f32x4_t* c, f32x4_t* d){
  asm volatile("global_load_dwordx4 %0, %4, off sc0 sc1\n\t"
               "global_load_dwordx4 %1, %5, off sc0 sc1\n\t"
               "global_load_dwordx4 %2, %6, off sc0 sc1\n\t"
               "global_load_dwordx4 %3, %7, off sc0 sc1\n\t"
               "s_waitcnt vmcnt(0)"
               : "=&v"(*a), "=&v"(*b), "=&v"(*c), "=&v"(*d)
               : "v"(p0), "v"(p1), "v"(p2), "v"(p3) : "memory");
}

// ---------------- small prep kernels ----------------

__global__ void k_cvt_pad(const float* src, u16* dst, int N, int srcK, int useK, int Np, int Kp){
  int i = blockIdx.x * blockDim.x + threadIdx.x;
  if (i >= Np * Kp) return;
  int n = i / Kp, k = i - n * Kp;
  float v = (n < N && k < useK) ? src[(size_t)n * srcK + k] : 0.f;
  dst[i] = f2bf(v);
}

// repack Whh [1024][256] f32 -> [ns(4)][g(4)][ct(4)][ks(8)][ln(64)][8] bf16
__global__ void k_repack(const float* src, u16* dst){
  int d = blockIdx.x * blockDim.x + threadIdx.x;   // 262144 total
  if (d >= 262144) return;
  int e  = d & 7;
  int ln = (d >> 3) & 63;
  int ks = (d >> 9) & 7;
  int ct = (d >> 12) & 3;
  int g  = (d >> 14) & 3;
  int ns = (d >> 16) & 3;
  int c = ns * 64 + ct * 16 + (ln & 15);
  int n = g * 256 + c;
  int k = ks * 32 + (ln >> 4) * 8 + e;
  dst[d] = f2bf(src[n * 256 + k]);
}

// repack merged [dWih1 | dWhh1] (1024 x 512) -> [ns8(8)][g(4)][ct(2)][ks(16)][ln(64)][8] bf16
__global__ void k_repack_cat(const float* Wih, const float* Whh, u16* dst){
  int d = blockIdx.x * blockDim.x + threadIdx.x;   // 524288 total
  if (d >= 524288) return;
  int e   = d & 7;
  int ln  = (d >> 3) & 63;
  int ks  = (d >> 9) & 15;
  int ct  = (d >> 13) & 1;
  int g   = (d >> 14) & 3;
  int ns8 = (d >> 16) & 7;
  int n = g * 256 + ns8 * 32 + ct * 16 + (ln & 15);
  int k = ks * 32 + (ln >> 4) * 8 + e;
  float v = (k < 256) ? Wih[(size_t)n * 256 + k] : Whh[(size_t)n * 256 + (k - 256)];
  dst[d] = f2bf(v);
}

__global__ void k_bias_sum(const float* a, const float* b, float* o, int n){
  int i = blockIdx.x * blockDim.x + threadIdx.x;
  if (i < n) o[i] = a[i] + b[i];
}

__global__ void k_zero(int* p, int n){
  int i = blockIdx.x * blockDim.x + threadIdx.x;
  if (i < n) p[i] = 0;
}

// ---------------- projection GEMM (writes G in MFMA C-frag layout) ----------------

struct ProjArgs {
  const u16* A; const u16* W;
  const float* colbias;
  u16* G;
  int Akp, K, t0, rev, Bg, bgLog;
};

template<int BK>
__global__ __launch_bounds__(256) void k_proj(ProjArgs p){
  constexpr int SLOTS = BK / 8;
  constexpr int SM = SLOTS - 1;
  constexpr int LOG = (BK == 64) ? 3 : 2;
  __shared__ __align__(16) u16 lA[128 * BK];
  __shared__ __align__(16) u16 lW[128 * BK];
  const int tid = threadIdx.x, lane = tid & 63, wid = tid >> 6;
  const int wm = wid >> 1, wn = wid & 1;
  const int mBase = blockIdx.x * 128;
  const int nBase = blockIdx.y * 128;
  const int t_rel = mBase >> p.bgLog;
  const int bBase = mBase & (p.Bg - 1);
  const int t_glob = p.t0 + t_rel;
  const int t_src = p.rev ? (TT - 1 - t_glob) : t_glob;

  f32x4_t acc[4][4];
#pragma unroll
  for (int m = 0; m < 4; ++m)
#pragma unroll
    for (int n = 0; n < 4; ++n) acc[m][n] = (f32x4_t){0.f, 0.f, 0.f, 0.f};

  for (int k0 = 0; k0 < p.K; k0 += BK){
#pragma unroll
    for (int i = 0; i < (128 * SLOTS) / 256; ++i){
      int idx = i * 256 + tid;
      int row = idx >> LOG, sl = idx & SM;
      bf16x8_t va = *(const bf16x8_t*)(p.A + (size_t)((bBase + row) * TT + t_src) * p.Akp + k0 + sl * 8);
      *(bf16x8_t*)&lA[((row << LOG) + (sl ^ (row & SM))) * 8] = va;
      bf16x8_t vw = *(const bf16x8_t*)(p.W + (size_t)(nBase + row) * p.K + k0 + sl * 8);
      *(bf16x8_t*)&lW[((row << LOG) + (sl ^ (row & SM))) * 8] = vw;
    }
    __syncthreads();
#pragma unroll
    for (int kk = 0; kk < BK; kk += 32){
      bf16x8_t af[4], wf[4];
#pragma unroll
      for (int m = 0; m < 4; ++m){
        int row = wm * 64 + m * 16 + (lane & 15);
        int sl = ((kk >> 3) + (lane >> 4)) ^ (row & SM);
        af[m] = *(const bf16x8_t*)&lA[((row << LOG) + sl) * 8];
      }
#pragma unroll
      for (int n = 0; n < 4; ++n){
        int row = wn * 64 + n * 16 + (lane & 15);
        int sl = ((kk >> 3) + (lane >> 4)) ^ (row & SM);
        wf[n] = *(const bf16x8_t*)&lW[((row << LOG) + sl) * 8];
      }
#pragma unroll
      for (int m = 0; m < 4; ++m)
#pragma unroll
        for (int n = 0; n < 4; ++n)
          acc[m][n] = MFMA(af[m], wf[n], acc[m][n]);
    }
    __syncthreads();
  }

  const int btiles = p.Bg >> 4;
#pragma unroll
  for (int m = 0; m < 4; ++m){
    int btile = (bBase + wm * 64 + m * 16) >> 4;
#pragma unroll
    for (int n = 0; n < 4; ++n){
      int coltile = nBase + wn * 64 + n * 16;
      int col = coltile + (lane & 15);
      int ntile = coltile >> 4;
      float cb = p.colbias ? p.colbias[col] : 0.f;
      bf16x4_t outv;
#pragma unroll
      for (int q = 0; q < 4; ++q)
        outv[q] = (short)f2bf(acc[m][n][q] + cb);
      *(bf16x4_t*)(p.G + ((((size_t)t_rel * btiles + btile) * 64 + ntile) * 64 + lane) * 4) = outv;
    }
  }
}

// ---------------- unified LSTM recurrence ----------------
// MODE 0: enc-l0 (x-fused, Y out, 2 dirs)     grid 2*nbt*4
// MODE 2: enc-l1 (G input, 2 dirs)            grid 2*nbt*4
// MODE 1: FUSED decoder: blocks [0, nbt*4) = dec-l0 (x+zconst), blocks [nbt*4, nbt*12) =
//         dec-l1 (8-way col split, merged K=512 matmul vs [y0d;h1], out-projection).
//         l1 stages y0d directly from l0's exchange; l0 throttled by l1 flags.

struct RecArgs {
  const u16* Wr0; const u16* Wr1;       // Whh slabs (MODE1: Wr0=l0 Whh, Wr1=Wcat)
  int* flg0; int* flg1;                 // MODE1: flg0=l0(4/bt), flg1=l1(8/bt)
  u16* hX0; u16* hX1;                   // MODE1: hX0=l0 exch, hX1=l1 exch
  const u16* G0; const u16* G1; int btilesG;
  const float* x; const int* labels; const float* emb; int gb0;
  const float* cb0; const float* cb1;   // MODE0 bias per dir; MODE1: cb1 = db1 (l1 bias)
  const u16* Wx0; const u16* Wx1;
  const u16* zcF;
  const u16* hI0; const u16* hI1;       // MODE1: hI0=dh0, hI1=dh1
  const float* cI0; const float* cI1;   // MODE1: cI0=dc0, cI1=dc1
  float* cS0; float* cS1;
  u16* hW0; u16* hW1;
  u16* Y; int ycols; int yoff0; int yoff1;
  const u16* Wo; const float* bo; float* outp;
  int t0, t1, nbt;
};

template<int MODE>
__global__ __launch_bounds__(512, 1) void k_rec(RecArgs a){
  constexpr bool ENC0 = (MODE == 0);
  constexpr bool DEC  = (MODE == 1);
  constexpr bool GIN  = (MODE == 2);
  constexpr bool XIN  = (MODE <= 1);

  __shared__ __align__(16) char S[163840];
  u16* Wlds = (u16*)S;                 // 128 KB
  u16* hlds = (u16*)(S + 131072);      // 16 KB (l1 role: staged y0d)
  u16* hl1  = (u16*)(S + 147456);      // 16 KB (l1 role only)
  u16* xT   = (u16*)(S + 147456);      // 2 KB (l0/enc roles; overlaps hl1)

  const int bx = blockIdx.x;
  const int tid = threadIdx.x;
  const int lane = tid & 63, w = tid >> 6;
  const int l15 = lane & 15, lhi = lane >> 4;

  // =========================== role: fused dec-l1 ===========================
  if (DEC && bx >= a.nbt * 4){
    const int idx = bx - a.nbt * 4;
    const int ns8 = idx & 7;
    const int bt = idx >> 3;
    const int bb = bt * 32;
    const int mt = (w >> 1) & 1, ct = w & 1;
    const int colb = ns8 * 32 + ct * 16 + l15;
    const u16* Wsrc = a.Wr1 + (size_t)ns8 * 65536;
    int* ownflg = a.flg1 + bt * 8;
    const int* l0flg = a.flg0 + bt * 4;
    u16* hXo = a.hX1 + (size_t)bt * 16384;
    const u16* hXl0 = a.hX0 + (size_t)bt * 16384;

    // stage Wcat slab 128 KB
#pragma unroll
    for (int i = 0; i < 16; ++i){
      int ix = i * 512 + tid;
      *(f32x4_t*)((char*)Wlds + (size_t)ix * 16) = *(const f32x4_t*)((const char*)Wsrc + (size_t)ix * 16);
    }
    float cfr[4], bias4[4];
    if (w < 4){
#pragma unroll
      for (int g = 0; g < 4; ++g) bias4[g] = a.cb1[g * 256 + colb];
#pragma unroll
      for (int q = 0; q < 4; ++q)
        cfr[q] = a.cI1[(size_t)(bb + mt * 16 + lhi * 4 + q) * 256 + colb];
    }
    bf16x8_t wo8[8];
    float bo = 0.f;
    if (ns8 == 0 && (w == 4 || w == 5)){
#pragma unroll
      for (int ks = 0; ks < 8; ++ks)
        wo8[ks] = *(const bf16x8_t*)(a.Wo + (size_t)l15 * 256 + ks * 32 + lhi * 8);
      if (l15 < 12) bo = a.bo[l15];
    }
    unsigned dsA[8];
#pragma unroll
    for (int ks = 0; ks < 8; ++ks)
      dsA[ks] = (unsigned)((((mt * 16 + l15) << 5) + (((ks << 2) + lhi) ^ (l15 & 7))) * 16);
    unsigned wrO[4];
    if (w < 4){
#pragma unroll
      for (int q = 0; q < 4; ++q){
        int row = mt * 16 + lhi * 4 + q;
        wrO[q] = (unsigned)((row << 9) + (((colb >> 3) ^ (row & 7)) << 4) + ((colb & 7) << 1));
      }
      // publish h1(0)
#pragma unroll
      for (int q = 0; q < 4; ++q){
        u16 hv = a.hI1[(size_t)(bb + mt * 16 + lhi * 4 + q) * 256 + colb];
        st_u16_sc((char*)hXo + wrO[q], hv);
      }
    }
    __syncthreads();
    if (tid == 0) st_flag(ownflg + ns8, 1);

    auto spinL1 = [&](int tOwn, int tL0, int useL0){
      if (w == 0){
        while (true){
          int f = 0x7fffffff, tgt = 0;
          if (lane < 8){ f = ld_flag(ownflg + lane); tgt = tOwn; }
          else if (lane < 12 && useL0){ f = ld_flag((const int*)l0flg + (lane - 8)); tgt = tL0; }
          if (__all(f >= tgt)) break;
          __builtin_amdgcn_s_sleep(2);
        }
      }
      __syncthreads();
    };
    auto stage2 = [&](int parA, int parB, int doA){
      int o0 = w * 2048 + lane * 16;
      const char* sB = (const char*)hXo + parB * 16384;
      f32x4_t v0, v1, v2, v3;
      if (doA){
        const char* sA = (const char*)hXl0 + parA * 16384;
        ld4_b128_sc(sA + o0, sA + o0 + 1024, sB + o0, sB + o0 + 1024, &v0, &v1, &v2, &v3);
        *(f32x4_t*)((char*)hlds + o0) = v0;
        *(f32x4_t*)((char*)hlds + o0 + 1024) = v1;
      } else {
        ld2_b128_sc(sB + o0, sB + o0 + 1024, &v2, &v3);
      }
      *(f32x4_t*)((char*)hl1 + o0) = v2;
      *(f32x4_t*)((char*)hl1 + o0 + 1024) = v3;
    };

    spinL1(1, 2, 1);
    stage2(1, 0, 1);           // y0d[0] = h_l0(1) parity 1; h1(0) parity 0
    __syncthreads();

    for (int t = 0; t < TT; ++t){
      // out-projection of h1(t) -> out[t-1]  (waves 4-5, ns8==0)
      if (ns8 == 0 && (w == 4 || w == 5) && t > 0){
        f32x4_t oa = (f32x4_t){0.f, 0.f, 0.f, 0.f};
#pragma unroll
        for (int ks = 0; ks < 8; ++ks){
          bf16x8_t af = *(const bf16x8_t*)((char*)hl1 + (w - 4) * 8192 + dsA[ks]);
          oa = MFMA(af, wo8[ks], oa);
        }
        if (l15 < 12){
#pragma unroll
          for (int q = 0; q < 4; ++q)
            a.outp[((size_t)(bb + (w - 4) * 16 + lhi * 4 + q) * TT + (t - 1)) * 12 + l15] = oa[q] + bo;
        }
      }
      const int par = (t + 1) & 1;
      if (w < 4){
        f32x4_t acc[4];
#pragma unroll
        for (int g = 0; g < 4; ++g) acc[g] = (f32x4_t){bias4[g], bias4[g], bias4[g], bias4[g]};
#pragma unroll
        for (int ks = 0; ks < 16; ++ks){
          bf16x8_t af = (ks < 8)
            ? *(const bf16x8_t*)((char*)hlds + dsA[ks])
            : *(const bf16x8_t*)((char*)hl1 + dsA[ks - 8]);
#pragma unroll
          for (int g = 0; g < 4; ++g){
            bf16x8_t bf = *(const bf16x8_t*)((char*)Wlds + ((g * 2 + ct) * 16 + ks) * 1024 + lane * 16);
            acc[g] = MFMA(af, bf, acc[g]);
          }
        }
#pragma unroll
        for (int q = 0; q < 4; ++q){
          float iv = sigm(acc[0][q]);
          float fv = sigm(acc[1][q]);
          float gv = tanh_(acc[2][q]);
          float ov = sigm(acc[3][q]);
          float c = fv * cfr[q] + iv * gv;
          cfr[q] = c;
          st_u16_sc((char*)hXo + par * 16384 + wrO[q], f2bf(ov * tanh_(c)));
        }
      }
      __syncthreads();
      if (tid == 0) st_flag(ownflg + ns8, t + 2);
      int more = (t + 1 < TT);
      spinL1(t + 2, t + 3, more);
      stage2(t & 1, par, more);
      __syncthreads();
    }
    // epilogue: h1(TT) -> out[TT-1]
    if (ns8 == 0 && (w == 4 || w == 5)){
      f32x4_t oa = (f32x4_t){0.f, 0.f, 0.f, 0.f};
#pragma unroll
      for (int ks = 0; ks < 8; ++ks){
        bf16x8_t af = *(const bf16x8_t*)((char*)hl1 + (w - 4) * 8192 + dsA[ks]);
        oa = MFMA(af, wo8[ks], oa);
      }
      if (l15 < 12){
#pragma unroll
        for (int q = 0; q < 4; ++q)
          a.outp[((size_t)(bb + (w - 4) * 16 + lhi * 4 + q) * TT + (TT - 1)) * 12 + l15] = oa[q] + bo;
      }
    }
    return;
  }

  // =========================== roles: enc-l0 / enc-l1 / dec-l0 ===========================
  const int ns = bx & 3;
  const int gid = bx >> 2;
  const int dir = DEC ? 0 : (gid / a.nbt);
  const int bt = DEC ? gid : (gid - dir * a.nbt);
  const int bb = bt * 32;
  const int mt = w >> 2, ct = w & 3;
  const int colb = ns * 64 + ct * 16 + l15;

  const u16* Wsrc = (dir ? a.Wr1 : a.Wr0) + (size_t)ns * 65536;
  int* flg = (dir ? a.flg1 : a.flg0) + bt * 4;
  const int* l1flg = DEC ? (a.flg1 + bt * 8) : nullptr;
  u16* hXg = (dir ? a.hX1 : a.hX0) + (size_t)bt * 16384;
  const int yoff = dir ? a.yoff1 : a.yoff0;

#pragma unroll
  for (int i = 0; i < 16; ++i){
    int ix = i * 512 + tid;
    *(f32x4_t*)((char*)Wlds + (size_t)ix * 16) = *(const f32x4_t*)((const char*)Wsrc + (size_t)ix * 16);
  }

  float cfr[4];
  {
    const float* cp = dir ? a.cI1 : a.cI0;
#pragma unroll
    for (int q = 0; q < 4; ++q)
      cfr[q] = cp ? cp[(size_t)(bb + mt * 16 + lhi * 4 + q) * 256 + colb] : 0.f;
  }

  float bias4[4];
  f32x4_t zcv[4];
  bf16x8_t wfx[4];
  if (ENC0){
    const float* cb = dir ? a.cb1 : a.cb0;
#pragma unroll
    for (int g = 0; g < 4; ++g) bias4[g] = cb[g * 256 + colb];
  }
  if (DEC){
#pragma unroll
    for (int g = 0; g < 4; ++g){
      int ntile = g * 16 + ns * 4 + ct;
      bf16x4_t zv = *(const bf16x4_t*)(a.zcF + ((((size_t)((bb >> 4) + mt)) * 64 + ntile) * 64 + lane) * 4);
      zcv[g] = cvt4(zv);
    }
  }
  if (XIN){
    const u16* Wx = dir ? a.Wx1 : a.Wx0;
#pragma unroll
    for (int g = 0; g < 4; ++g)
      wfx[g] = *(const bf16x8_t*)(Wx + (size_t)(g * 256 + colb) * 32 + lhi * 8);
  }

  if (XIN){
    int row = tid >> 4, c16 = tid & 15;
    int gr = a.gb0 + bb + row;
    u16 vA = 0, vB = 0;
    if (!DEC){
      int lb = a.labels[gr];
      if (c16 >= 12) vA = f2bf(a.emb[lb * 8 + (c16 - 12)]);
      if (c16 < 4)   vB = f2bf(a.emb[lb * 8 + 4 + c16]);
    }
    u16 x0 = 0;
    if (!DEC && c16 < 12){
      int t0src = dir ? (TT - 1) : 0;
      x0 = f2bf(a.x[((size_t)gr * TT + t0src) * 12 + c16]);
    }
    xT[row * 32 + c16] = (c16 < 12) ? x0 : vA;
    xT[row * 32 + 16 + c16] = vB;
  }

  unsigned dsA[8];
#pragma unroll
  for (int ks = 0; ks < 8; ++ks)
    dsA[ks] = (unsigned)((((mt * 16 + l15) << 5) + (((ks << 2) + lhi) ^ (l15 & 7))) * 16);
  unsigned wrO[4];
#pragma unroll
  for (int q = 0; q < 4; ++q){
    int row = mt * 16 + lhi * 4 + q;
    wrO[q] = (unsigned)((row << 9) + (((colb >> 3) ^ (row & 7)) << 4) + ((colb & 7) << 1));
  }
  const char* Gc = GIN ? (const char*)(dir ? a.G1 : a.G0) : nullptr;
  unsigned gOff[4];
  const unsigned gstep = (unsigned)a.btilesG * 32768u;
  bf16x4_t gvP[4];
  if (GIN){
#pragma unroll
    for (int g = 0; g < 4; ++g){
      int ntile = g * 16 + ns * 4 + ct;
      gOff[g] = (unsigned)((((bb >> 4) + mt) * 64 + ntile) * 512 + lane * 8);
    }
#pragma unroll
    for (int g = 0; g < 4; ++g)
      gvP[g] = *(const bf16x4_t*)(Gc + gOff[g]);
  }

  if (a.t0 == 0){
    const u16* hp = dir ? a.hI1 : a.hI0;
    const u16* hq = DEC ? a.hI0 : hp;
#pragma unroll
    for (int q = 0; q < 4; ++q){
      u16 hv = hq ? hq[(size_t)(bb + mt * 16 + lhi * 4 + q) * 256 + colb] : (u16)0;
      st_u16_sc((char*)hXg + wrO[q], hv);
    }
  }
  __syncthreads();
  if (tid == 0 && a.t0 == 0) st_flag(flg + ns, 1);

  auto spin_to = [&](int tOwn, int tL1){
    if (w == 0){
      while (true){
        int f = 0x7fffffff, tgt = 0;
        if (lane < 4){ f = ld_flag(flg + lane); tgt = tOwn; }
        else if (DEC && lane < 12){ f = ld_flag((const int*)l1flg + (lane - 4)); tgt = tL1; }
        if (__all(f >= tgt)) break;
        __builtin_amdgcn_s_sleep(2);
      }
    }
    __syncthreads();
  };
  auto stage_h = [&](int par){
    const char* src = (const char*)hXg + par * 16384;
    int o0 = w * 2048 + lane * 16;
    f32x4_t v0, v1;
    ld2_b128_sc(src + o0, src + o0 + 1024, &v0, &v1);
    *(f32x4_t*)((char*)hlds + o0) = v0;
    *(f32x4_t*)((char*)hlds + o0 + 1024) = v1;
  };

  spin_to(a.t0 + 1, 0);
  stage_h(a.t0 & 1);
  __syncthreads();

  for (int t = a.t0; t < a.t1; ++t){
    f32x4_t acc[4];
    if (GIN){
#pragma unroll
      for (int g = 0; g < 4; ++g) acc[g] = cvt4(gvP[g]);
    } else if (DEC){
#pragma unroll
      for (int g = 0; g < 4; ++g) acc[g] = zcv[g];
    } else {
#pragma unroll
      for (int g = 0; g < 4; ++g) acc[g] = (f32x4_t){bias4[g], bias4[g], bias4[g], bias4[g]};
    }
    if (XIN){
      bf16x8_t ax = *(const bf16x8_t*)((char*)xT + (mt * 16 + l15) * 64 + lhi * 16);
#pragma unroll
      for (int g = 0; g < 4; ++g) acc[g] = MFMA(ax, wfx[g], acc[g]);
    }
#pragma unroll
    for (int ks = 0; ks < 8; ++ks){
      bf16x8_t af = *(const bf16x8_t*)((char*)hlds + dsA[ks]);
#pragma unroll
      for (int g = 0; g < 4; ++g){
        bf16x8_t bf = *(const bf16x8_t*)((char*)Wlds + ((g * 4 + ct) * 8 + ks) * 1024 + lane * 16);
        acc[g] = MFMA(af, bf, acc[g]);
      }
    }
    const int par = (t + 1) & 1;
    u16 hbv[4];
#pragma unroll
    for (int q = 0; q < 4; ++q){
      float iv = sigm(acc[0][q]);
      float fv = sigm(acc[1][q]);
      float gv = tanh_(acc[2][q]);
      float ov = sigm(acc[3][q]);
      float c = fv * cfr[q] + iv * gv;
      cfr[q] = c;
      u16 hb = f2bf(ov * tanh_(c));
      hbv[q] = hb;
      st_u16_sc((char*)hXg + par * 16384 + wrO[q], hb);
    }
    __syncthreads();
    if (tid == 0) st_flag(flg + ns, t + 2);
    if (ENC0){
      const int ty = dir ? (TT - 1 - t) : t;
#pragma unroll
      for (int q = 0; q < 4; ++q)
        a.Y[((size_t)(bb + mt * 16 + lhi * 4 + q) * TT + ty) * a.ycols + yoff + colb] = hbv[q];
    }
    if (GIN){
#pragma unroll
      for (int g = 0; g < 4; ++g) gOff[g] += gstep;
      if (t + 1 < a.t1){
#pragma unroll
        for (int g = 0; g < 4; ++g)
          gvP[g] = *(const bf16x4_t*)(Gc + gOff[g]);
      }
    }
    spin_to(t + 2, t + 1);
    stage_h(par);
    if (XIN && (t + 1) < a.t1){
      if (tid < 128 && (tid & 3) < 3){
        int row = tid >> 2, xq = tid & 3;
        int tsrc = DEC ? t : (dir ? (TT - 2 - t) : (t + 1));
        f32x4_t xv = *(const f32x4_t*)(a.x + ((size_t)(a.gb0 + bb + row) * TT + tsrc) * 12 + xq * 4);
        bf16x4_t xb;
#pragma unroll
        for (int e = 0; e < 4; ++e) xb[e] = (short)f2bf(xv[e]);
        *(bf16x4_t*)((char*)xT + row * 64 + xq * 8) = xb;
      }
    }
    __syncthreads();
  }

  {
    float* cs = dir ? a.cS1 : a.cS0;
    if (cs){
#pragma unroll
      for (int q = 0; q < 4; ++q)
        cs[(size_t)(bb + mt * 16 + lhi * 4 + q) * 256 + colb] = cfr[q];
    }
    u16* hw = dir ? a.hW1 : a.hW0;
    if (hw){
#pragma unroll
      for (int q = 0; q < 4; ++q){
        u16 hv = *(u16*)((char*)hlds + wrO[q]);
        hw[(size_t)(bb + mt * 16 + lhi * 4 + q) * 256 + colb] = hv;
      }
    }
  }
}

// ---------------- mid kernels ----------------

__global__ void k_mulv(const u16* sH0, const u16* sH1,
                       const float* Wmu, const float* bmu,
                       const float* Wlv, const float* blv, float* mulv){
  int i = blockIdx.x * blockDim.x + threadIdx.x;
  if (i >= BFULL * 128) return;
  int b = i >> 7, j = i & 127;
  const float* W = (j < 64) ? (Wmu + (size_t)j * 512) : (Wlv + (size_t)(j - 64) * 512);
  float s = (j < 64) ? bmu[j] : blv[j - 64];
  for (int k = 0; k < 256; ++k) s += bf2f(sH0[(size_t)b * 256 + k]) * W[k];
  for (int k = 0; k < 256; ++k) s += bf2f(sH1[(size_t)b * 256 + k]) * W[256 + k];
  mulv[i] = s;
}

__global__ void k_sample(const float* mulv, const float* eps, const int* labels, const float* emb,
                         float* out_mu, float* out_lv, float* out_z, float* zcf){
  int i = blockIdx.x * blockDim.x + threadIdx.x;
  if (i >= BFULL * 128) return;
  int b = i >> 7, j = i & 127;
  if (j < 64){
    float mu = mulv[b * 128 + j];
    float lv = mulv[b * 128 + 64 + j];
    float z = mu + eps[b * 64 + j] * __expf(0.5f * lv);
    out_mu[b * 64 + j] = mu;
    out_lv[b * 64 + j] = lv;
    out_z[b * 64 + j] = z;
    zcf[i] = z;
  } else if (j < 72){
    zcf[i] = emb[labels[b] * 8 + (j - 64)];
  } else {
    zcf[i] = 0.f;
  }
}

__global__ void k_hc(const float* zcf, const float* Whid, const float* bhid,
                     const float* Wcell, const float* bcell, float* HC){
  int i = blockIdx.x * blockDim.x + threadIdx.x;
  if (i >= BFULL * 1024) return;
  int b = i >> 10, n = i & 1023;
  const float* W; float s;
  if (n < 512){ W = Whid + (size_t)n * 72; s = bhid[n]; }
  else        { W = Wcell + (size_t)(n - 512) * 72; s = bcell[n - 512]; }
  for (int k = 0; k < 72; ++k) s += zcf[b * 128 + k] * W[k];
  HC[i] = s;
}

__global__ void k_zconst(const float* zcf, const float* dWih0,
                         const float* dbih0, const float* dbhh0, float* zconst){
  int i = blockIdx.x * blockDim.x + threadIdx.x;
  if (i >= BFULL * 1024) return;
  int b = i >> 10, n = i & 1023;
  float s = dbih0[n] + dbhh0[n];
  const float* W = dWih0 + (size_t)n * 84 + 12;
  for (int k = 0; k < 72; ++k) s += zcf[b * 128 + k] * W[k];
  zconst[i] = s;
}

__global__ void k_zfrag(const float* zconst, u16* zcF){
  int i = blockIdx.x * blockDim.x + threadIdx.x;
  if (i >= BFULL * GH) return;
  int q = i & 3, ln = (i >> 2) & 63, nt = (i >> 8) & 63, bt = i >> 14;
  int r = bt * 16 + (ln >> 4) * 4 + q;
  int col = nt * 16 + (ln & 15);
  zcF[i] = f2bf(zconst[(size_t)r * GH + col]);
}

// faithful torch .view(NL, B, H) on [B, NL*H]
__global__ void k_dec_init(const float* HC, u16* h0, float* c0, u16* h1, float* c1){
  int i = blockIdx.x * blockDim.x + threadIdx.x;
  if (i >= BFULL * 256) return;
  int b = i >> 8, h = i & 255;
  int col = (b & 1) * 256 + h;
  int r0 = b >> 1;
  int r1 = 256 + (b >> 1);
  h0[i] = f2bf(HC[(size_t)r0 * 1024 + col]);
  c0[i] =      HC[(size_t)r0 * 1024 + 512 + col];
  h1[i] = f2bf(HC[(size_t)r1 * 1024 + col]);
  c1[i] =      HC[(size_t)r1 * 1024 + 512 + col];
}

// ---------------- host ----------------

static inline size_t alignup(size_t x){ return (x + 255) & ~(size_t)255; }
static inline int ilog2(int x){ return 31 - __builtin_clz((unsigned)x); }

extern "C" void kernel_launch(void* const* d_in, const int* in_sizes, int n_in,
                              void* d_out, int out_size, void* d_ws, size_t ws_size,
                              hipStream_t stream){
  const float* x      = (const float*)d_in[0];
  const int*   labels = (const int*)  d_in[1];
  const float* eps    = (const float*)d_in[2];
  const float* emb    = (const float*)d_in[3];
  const float* Wih0f = (const float*)d_in[4],  *Whh0f = (const float*)d_in[5];
  const float* bih0f = (const float*)d_in[6],  *bhh0f = (const float*)d_in[7];
  const float* Wih0b = (const float*)d_in[8],  *Whh0b = (const float*)d_in[9];
  const float* bih0b = (const float*)d_in[10], *bhh0b = (const float*)d_in[11];
  const float* Wih1f = (const float*)d_in[12], *Whh1f = (const float*)d_in[13];
  const float* bih1f = (const float*)d_in[14], *bhh1f = (const float*)d_in[15];
  const float* Wih1b = (const float*)d_in[16], *Whh1b = (const float*)d_in[17];
  const float* bih1b = (const float*)d_in[18], *bhh1b = (const float*)d_in[19];
  const float* Wmu = (const float*)d_in[20], *bmu = (const float*)d_in[21];
  const float* Wlv = (const float*)d_in[22], *blv = (const float*)d_in[23];
  const float* Whid = (const float*)d_in[24], *bhid = (const float*)d_in[25];
  const float* Wcell = (const float*)d_in[26], *bcell = (const float*)d_in[27];
  const float* dWih0 = (const float*)d_in[28], *dWhh0 = (const float*)d_in[29];
  const float* dbih0 = (const float*)d_in[30], *dbhh0 = (const float*)d_in[31];
  const float* dWih1 = (const float*)d_in[32], *dWhh1 = (const float*)d_in[33];
  const float* dbih1 = (const float*)d_in[34], *dbhh1 = (const float*)d_in[35];
  const float* Wout = (const float*)d_in[36], *bout = (const float*)d_in[37];

  float* out = (float*)d_out;
  float* out_mu = out + (size_t)BFULL * TT * 12;
  float* out_lv = out_mu + (size_t)BFULL * 64;
  float* out_z  = out_lv + (size_t)BFULL * 64;

  char* ws = (char*)d_ws; size_t off = 0;
  auto alloc = [&](size_t bytes)->char*{ char* p = ws + off; off += alignup(bytes); return p; };

  u16* W0f_b  = (u16*)alloc(1024 * 32 * 2);
  u16* W0b_b  = (u16*)alloc(1024 * 32 * 2);
  u16* dWx_b  = (u16*)alloc(1024 * 32 * 2);
  u16* Wo_b   = (u16*)alloc(16 * 256 * 2);
  u16* Whh0f_r = (u16*)alloc((size_t)1024 * 256 * 2);
  u16* Whh0b_r = (u16*)alloc((size_t)1024 * 256 * 2);
  u16* Whh1f_r = (u16*)alloc((size_t)1024 * 256 * 2);
  u16* Whh1b_r = (u16*)alloc((size_t)1024 * 256 * 2);
  u16* dWhh0_r = (u16*)alloc((size_t)1024 * 256 * 2);
  u16* Wcat_r  = (u16*)alloc((size_t)1024 * 512 * 2);
  u16* Wih1f_b = (u16*)alloc((size_t)1024 * 512 * 2);
  u16* Wih1b_b = (u16*)alloc((size_t)1024 * 512 * 2);
  float* b0f = (float*)alloc(1024 * 4);
  float* b0b = (float*)alloc(1024 * 4);
  float* b1f = (float*)alloc(1024 * 4);
  float* b1b = (float*)alloc(1024 * 4);
  float* db1 = (float*)alloc(1024 * 4);
  u16*  sHe1 = (u16*)alloc((size_t)2 * BFULL * 256 * 2);
  float* sCe1 = (float*)alloc((size_t)2 * BFULL * 256 * 4);
  u16*  dh0 = (u16*)alloc((size_t)BFULL * 256 * 2);
  float* dc0 = (float*)alloc((size_t)BFULL * 256 * 4);
  u16*  dh1 = (u16*)alloc((size_t)BFULL * 256 * 2);
  float* dc1 = (float*)alloc((size_t)BFULL * 256 * 4);
  float* mulv = (float*)alloc((size_t)BFULL * 128 * 4);
  float* zcf  = (float*)alloc((size_t)BFULL * 128 * 4);
  float* HC   = (float*)alloc((size_t)BFULL * 1024 * 4);
  float* zconst = (float*)alloc((size_t)BFULL * 1024 * 4);
  u16*  zcF   = (u16*)alloc((size_t)BFULL * 1024 * 2);
  int*  flagsA = (int*)alloc(768 * 4);                         // [layer][dir][bt][ns] + l1 flags
  int*  flagsB = flagsA + 512;                                 // [bt16][ns8]
  u16*  hXA    = (u16*)alloc((size_t)2 * 16 * 16384 * 2);      // [slot2][bt16][2par][8192]

  size_t rem = (ws_size > off + (1 << 20)) ? ws_size - off - (1 << 20) : 0;
  int eb = 128, Tc = 2;
  {
    const int sch[][2] = {
      {512,360},{512,120},{512,40},{512,24},{512,12},{512,8},
      {256,360},{256,120},{256,40},{256,12},{256,8},
      {128,360},{128,40},{128,8},{128,2}};
    for (int i = 0; i < (int)(sizeof(sch)/sizeof(sch[0])); ++i){
      size_t need = alignup((size_t)sch[i][0] * TT * 512 * 2)
                  + 2 * alignup((size_t)sch[i][1] * sch[i][0] * GH * 2);
      if (need <= rem){ eb = sch[i][0]; Tc = sch[i][1]; break; }
    }
  }
  const int ebLog = ilog2(eb);
  const int nGroups = BFULL / eb;
  const int nbt = eb / 32;

  u16* y0 = (u16*)alloc((size_t)eb * TT * 512 * 2);
  u16* Gf = (u16*)alloc((size_t)Tc * eb * GH * 2);
  u16* Gb = (u16*)alloc((size_t)Tc * eb * GH * 2);

  auto cvt = [&](const float* src, u16* dst, int N, int srcK, int useK, int Np, int Kp){
    int tot = Np * Kp;
    k_cvt_pad<<<(tot + 255) / 256, 256, 0, stream>>>(src, dst, N, srcK, useK, Np, Kp);
  };
  auto repack = [&](const float* src, u16* dst){
    k_repack<<<1024, 256, 0, stream>>>(src, dst);
  };
  auto bsum = [&](const float* a, const float* b, float* o){
    k_bias_sum<<<4, 256, 0, stream>>>(a, b, o, 1024);
  };
  auto proj = [&](const u16* A, int Akp, int K, const u16* W, const float* cbp,
                  u16* G, int t0, int tc, int rev){
    ProjArgs pa; pa.A = A; pa.W = W; pa.colbias = cbp; pa.G = G;
    pa.Akp = Akp; pa.K = K; pa.t0 = t0; pa.rev = rev; pa.Bg = eb; pa.bgLog = ebLog;
    dim3 grid(tc * (eb / 128), 8);
    k_proj<64><<<grid, 256, 0, stream>>>(pa);
  };
  auto flgbase = [&](int layer, int d, int gb0){ return flagsA + ((layer * 2 + d) * 16 + (gb0 >> 5)) * 4; };
  auto hxbase  = [&](int d, int gb0){ return hXA + ((size_t)d * 16 + (gb0 >> 5)) * 16384; };

  k_zero<<<3, 256, 0, stream>>>(flagsA, 768);
  cvt(Wih0f, W0f_b, 1024, 20, 20, 1024, 32);
  cvt(Wih0b, W0b_b, 1024, 20, 20, 1024, 32);
  cvt(dWih0, dWx_b, 1024, 84, 12, 1024, 32);
  cvt(Wout,  Wo_b,  12, 256, 256, 16, 256);
  repack(Whh0f, Whh0f_r);
  repack(Whh0b, Whh0b_r);
  repack(Whh1f, Whh1f_r);
  repack(Whh1b, Whh1b_r);
  repack(dWhh0, dWhh0_r);
  k_repack_cat<<<2048, 256, 0, stream>>>(dWih1, dWhh1, Wcat_r);
  cvt(Wih1f, Wih1f_b, 1024, 512, 512, 1024, 512);
  cvt(Wih1b, Wih1b_b, 1024, 512, 512, 1024, 512);
  bsum(bih0f, bhh0f, b0f);
  bsum(bih0b, bhh0b, b0b);
  bsum(bih1f, bhh1f, b1f);
  bsum(bih1b, bhh1b, b1b);
  bsum(dbih1, dbhh1, db1);

  // ---- encoder ----
  for (int g = 0; g < nGroups; ++g){
    int gb0 = g * eb;
    {
      RecArgs ra = {};
      ra.Wr0 = Whh0f_r; ra.Wr1 = Whh0b_r;
      ra.flg0 = flgbase(0, 0, gb0); ra.flg1 = flgbase(0, 1, gb0);
      ra.hX0 = hxbase(0, gb0); ra.hX1 = hxbase(1, gb0);
      ra.x = x; ra.labels = labels; ra.emb = emb; ra.gb0 = gb0;
      ra.cb0 = b0f; ra.cb1 = b0b;
      ra.Wx0 = W0f_b; ra.Wx1 = W0b_b;
      ra.Y = y0; ra.ycols = 512; ra.yoff0 = 0; ra.yoff1 = 256;
      ra.t0 = 0; ra.t1 = TT; ra.nbt = nbt;
      k_rec<0><<<2 * nbt * 4, 512, 0, stream>>>(ra);
    }
    for (int t0 = 0; t0 < TT; t0 += Tc){
      int t1 = (t0 + Tc < TT) ? t0 + Tc : TT; int tc = t1 - t0;
      proj(y0, 512, 512, Wih1f_b, b1f, Gf, t0, tc, 0);
      proj(y0, 512, 512, Wih1b_b, b1b, Gb, t0, tc, 1);
      RecArgs ra = {};
      ra.Wr0 = Whh1f_r; ra.Wr1 = Whh1b_r;
      ra.flg0 = flgbase(1, 0, gb0); ra.flg1 = flgbase(1, 1, gb0);
      ra.hX0 = hxbase(0, gb0); ra.hX1 = hxbase(1, gb0);
      ra.G0 = Gf; ra.G1 = Gb; ra.btilesG = eb >> 4;
      ra.cI0 = t0 ? (sCe1 + (size_t)gb0 * 256) : nullptr;
      ra.cI1 = t0 ? (sCe1 + (size_t)BFULL * 256 + (size_t)gb0 * 256) : nullptr;
      ra.cS0 = sCe1 + (size_t)gb0 * 256;
      ra.cS1 = sCe1 + (size_t)BFULL * 256 + (size_t)gb0 * 256;
      ra.hW0 = sHe1 + (size_t)gb0 * 256;
      ra.hW1 = sHe1 + (size_t)BFULL * 256 + (size_t)gb0 * 256;
      ra.t0 = t0; ra.t1 = t1; ra.nbt = nbt;
      k_rec<2><<<2 * nbt * 4, 512, 0, stream>>>(ra);
    }
  }

  // ---- VAE head + decoder init ----
  k_mulv<<<(BFULL * 128) / 256, 256, 0, stream>>>(sHe1, sHe1 + (size_t)BFULL * 256,
                                                  Wmu, bmu, Wlv, blv, mulv);
  k_sample<<<(BFULL * 128) / 256, 256, 0, stream>>>(mulv, eps, labels, emb,
                                                    out_mu, out_lv, out_z, zcf);
  k_hc<<<(BFULL * 1024) / 256, 256, 0, stream>>>(zcf, Whid, bhid, Wcell, bcell, HC);
  k_zconst<<<(BFULL * 1024) / 256, 256, 0, stream>>>(zcf, dWih0, dbih0, dbhh0, zconst);
  k_zfrag<<<(BFULL * GH) / 256, 256, 0, stream>>>(zconst, zcF);
  k_dec_init<<<(BFULL * 256) / 256, 256, 0, stream>>>(HC, dh0, dc0, dh1, dc1);

  // ---- decoder (fused l0+l1 pipeline) ----
  for (int g = 0; g < nGroups; ++g){
    int gb0 = g * eb;
    RecArgs ra = {};
    ra.Wr0 = dWhh0_r; ra.Wr1 = Wcat_r;
    ra.flg0 = flgbase(2, 0, gb0); ra.flg1 = flagsB + (gb0 >> 5) * 8;
    ra.hX0 = hxbase(0, gb0); ra.hX1 = hxbase(1, gb0);
    ra.x = x; ra.gb0 = gb0;
    ra.zcF = zcF + ((size_t)(gb0 >> 4)) * 16384;
    ra.Wx0 = dWx_b; ra.Wx1 = dWx_b;
    ra.hI0 = dh0 + (size_t)gb0 * 256;
    ra.cI0 = dc0 + (size_t)gb0 * 256;
    ra.hI1 = dh1 + (size_t)gb0 * 256;
    ra.cI1 = dc1 + (size_t)gb0 * 256;
    ra.cb1 = db1;
    ra.Wo = Wo_b; ra.bo = bout;
    ra.outp = out + (size_t)gb0 * TT * 12;
    ra.t0 = 0; ra.t1 = TT; ra.nbt = nbt;
    k_rec<1><<<nbt * 12, 512, 0, stream>>>(ra);
  }
}

// Round 14
// 4931.923 us; speedup vs baseline: 1.3305x; 1.0008x over previous
//
#include <hip/hip_runtime.h>
#include <cstdint>
#include <cstddef>

#define TT 360
#define BFULL 512
#define GH 1024   /* 4*H */

typedef unsigned short u16;
typedef short bf16x8_t __attribute__((ext_vector_type(8)));
typedef short bf16x4_t __attribute__((ext_vector_type(4)));
typedef float f32x4_t  __attribute__((ext_vector_type(4)));

#define MFMA(A,B,C) __builtin_amdgcn_mfma_f32_16x16x32_bf16(A,B,C,0,0,0)

__device__ __forceinline__ float bf2f(u16 u){
  union { unsigned u; float f; } v; v.u = ((unsigned)u) << 16; return v.f;
}
__device__ __forceinline__ u16 f2bf(float f){
  union { float f; unsigned u; } v; v.f = f;
  unsigned r = v.u + 0x7FFFu + ((v.u >> 16) & 1u);
  return (u16)(r >> 16);
}
__device__ __forceinline__ float sigm(float x){
  float e = __builtin_amdgcn_exp2f(-1.44269504089f * x);
  return __builtin_amdgcn_rcpf(1.f + e);
}
__device__ __forceinline__ float tanh_(float x){
  float e = __builtin_amdgcn_exp2f(-2.88539008178f * x);
  return 2.f * __builtin_amdgcn_rcpf(1.f + e) - 1.f;
}
__device__ __forceinline__ f32x4_t cvt4(bf16x4_t v){
  f32x4_t r;
#pragma unroll
  for (int i = 0; i < 4; ++i) r[i] = bf2f((u16)v[i]);
  return r;
}

// ---- device-coherent ops for cross-block exchange ----
__device__ __forceinline__ void st_u16_sc(void* p, u16 v){
  asm volatile("global_store_short %0, %1, off sc0 sc1" :: "v"(p), "v"(v) : "memory");
}
__device__ __forceinline__ void st_flag(int* p, int v){
  asm volatile("global_store_dword %0, %1, off sc0 sc1" :: "v"(p), "v"(v) : "memory");
}
__device__ __forceinline__ int ld_flag(const int* p){
  int v;
  asm volatile("global_load_dword %0, %1, off sc0 sc1\n\ts_waitcnt vmcnt(0)"
               : "=v"(v) : "v"(p) : "memory");
  return v;
}
__device__ __forceinline__ void ld2_b128_sc(const void* p0, const void* p1, f32x4_t* a, f32x4_t* b){
  asm volatile("global_load_dwordx4 %0, %2, off sc0 sc1\n\t"
               "global_load_dwordx4 %1, %3, off sc0 sc1\n\t"
               "s_waitcnt vmcnt(0)"
               : "=&v"(*a), "=&v"(*b) : "v"(p0), "v"(p1) : "memory");
}
__device__ __forceinline__ void ld4_b128_sc(const void* p0, const void* p1, const void* p2, const void* p3,
                                            f32x4_t* a, f32x4_t* b, f32x4_t* c, f32x4_t* d){
  asm volatile("global_load_dwordx4 %0, %4, off sc0 sc1\n\t"
               "global_load_dwordx4 %1, %5, off sc0 sc1\n\t"
               "global_load_dwordx4 %2, %6, off sc0 sc1\n\t"
               "global_load_dwordx4 %3, %7, off sc0 sc1\n\t"
               "s_waitcnt vmcnt(0)"
               : "=&v"(*a), "=&v"(*b), "=&v"(*c), "=&v"(*d)
               : "v"(p0), "v"(p1), "v"(p2), "v"(p3) : "memory");
}

// ---------------- small prep kernels ----------------

__global__ void k_cvt_pad(const float* src, u16* dst, int N, int srcK, int useK, int Np, int Kp){
  int i = blockIdx.x * blockDim.x + threadIdx.x;
  if (i >= Np * Kp) return;
  int n = i / Kp, k = i - n * Kp;
  float v = (n < N && k < useK) ? src[(size_t)n * srcK + k] : 0.f;
  dst[i] = f2bf(v);
}

// repack Whh [1024][256] f32 -> [ns(4)][g(4)][ct(4)][ks(8)][ln(64)][8] bf16
__global__ void k_repack(const float* src, u16* dst){
  int d = blockIdx.x * blockDim.x + threadIdx.x;   // 262144 total
  if (d >= 262144) return;
  int e  = d & 7;
  int ln = (d >> 3) & 63;
  int ks = (d >> 9) & 7;
  int ct = (d >> 12) & 3;
  int g  = (d >> 14) & 3;
  int ns = (d >> 16) & 3;
  int c = ns * 64 + ct * 16 + (ln & 15);
  int n = g * 256 + c;
  int k = ks * 32 + (ln >> 4) * 8 + e;
  dst[d] = f2bf(src[n * 256 + k]);
}

// repack merged [dWih1 | dWhh1] (1024 x 512) -> [ns8(8)][g(4)][ct(2)][ks(16)][ln(64)][8] bf16
__global__ void k_repack_cat(const float* Wih, const float* Whh, u16* dst){
  int d = blockIdx.x * blockDim.x + threadIdx.x;   // 524288 total
  if (d >= 524288) return;
  int e   = d & 7;
  int ln  = (d >> 3) & 63;
  int ks  = (d >> 9) & 15;
  int ct  = (d >> 13) & 1;
  int g   = (d >> 14) & 3;
  int ns8 = (d >> 16) & 7;
  int n = g * 256 + ns8 * 32 + ct * 16 + (ln & 15);
  int k = ks * 32 + (ln >> 4) * 8 + e;
  float v = (k < 256) ? Wih[(size_t)n * 256 + k] : Whh[(size_t)n * 256 + (k - 256)];
  dst[d] = f2bf(v);
}

__global__ void k_bias_sum(const float* a, const float* b, float* o, int n){
  int i = blockIdx.x * blockDim.x + threadIdx.x;
  if (i < n) o[i] = a[i] + b[i];
}

__global__ void k_zero(int* p, int n){
  int i = blockIdx.x * blockDim.x + threadIdx.x;
  if (i < n) p[i] = 0;
}

// ---------------- projection GEMM (writes G in MFMA C-frag layout) ----------------

struct ProjArgs {
  const u16* A; const u16* W;
  const float* colbias;
  u16* G;
  int Akp, K, t0, rev, Bg, bgLog;
};

template<int BK>
__global__ __launch_bounds__(256) void k_proj(ProjArgs p){
  constexpr int SLOTS = BK / 8;
  constexpr int SM = SLOTS - 1;
  constexpr int LOG = (BK == 64) ? 3 : 2;
  __shared__ __align__(16) u16 lA[128 * BK];
  __shared__ __align__(16) u16 lW[128 * BK];
  const int tid = threadIdx.x, lane = tid & 63, wid = tid >> 6;
  const int wm = wid >> 1, wn = wid & 1;
  const int mBase = blockIdx.x * 128;
  const int nBase = blockIdx.y * 128;
  const int t_rel = mBase >> p.bgLog;
  const int bBase = mBase & (p.Bg - 1);
  const int t_glob = p.t0 + t_rel;
  const int t_src = p.rev ? (TT - 1 - t_glob) : t_glob;

  f32x4_t acc[4][4];
#pragma unroll
  for (int m = 0; m < 4; ++m)
#pragma unroll
    for (int n = 0; n < 4; ++n) acc[m][n] = (f32x4_t){0.f, 0.f, 0.f, 0.f};

  for (int k0 = 0; k0 < p.K; k0 += BK){
#pragma unroll
    for (int i = 0; i < (128 * SLOTS) / 256; ++i){
      int idx = i * 256 + tid;
      int row = idx >> LOG, sl = idx & SM;
      bf16x8_t va = *(const bf16x8_t*)(p.A + (size_t)((bBase + row) * TT + t_src) * p.Akp + k0 + sl * 8);
      *(bf16x8_t*)&lA[((row << LOG) + (sl ^ (row & SM))) * 8] = va;
      bf16x8_t vw = *(const bf16x8_t*)(p.W + (size_t)(nBase + row) * p.K + k0 + sl * 8);
      *(bf16x8_t*)&lW[((row << LOG) + (sl ^ (row & SM))) * 8] = vw;
    }
    __syncthreads();
#pragma unroll
    for (int kk = 0; kk < BK; kk += 32){
      bf16x8_t af[4], wf[4];
#pragma unroll
      for (int m = 0; m < 4; ++m){
        int row = wm * 64 + m * 16 + (lane & 15);
        int sl = ((kk >> 3) + (lane >> 4)) ^ (row & SM);
        af[m] = *(const bf16x8_t*)&lA[((row << LOG) + sl) * 8];
      }
#pragma unroll
      for (int n = 0; n < 4; ++n){
        int row = wn * 64 + n * 16 + (lane & 15);
        int sl = ((kk >> 3) + (lane >> 4)) ^ (row & SM);
        wf[n] = *(const bf16x8_t*)&lW[((row << LOG) + sl) * 8];
      }
#pragma unroll
      for (int m = 0; m < 4; ++m)
#pragma unroll
        for (int n = 0; n < 4; ++n)
          acc[m][n] = MFMA(af[m], wf[n], acc[m][n]);
    }
    __syncthreads();
  }

  const int btiles = p.Bg >> 4;
#pragma unroll
  for (int m = 0; m < 4; ++m){
    int btile = (bBase + wm * 64 + m * 16) >> 4;
#pragma unroll
    for (int n = 0; n < 4; ++n){
      int coltile = nBase + wn * 64 + n * 16;
      int col = coltile + (lane & 15);
      int ntile = coltile >> 4;
      float cb = p.colbias ? p.colbias[col] : 0.f;
      bf16x4_t outv;
#pragma unroll
      for (int q = 0; q < 4; ++q)
        outv[q] = (short)f2bf(acc[m][n][q] + cb);
      *(bf16x4_t*)(p.G + ((((size_t)t_rel * btiles + btile) * 64 + ntile) * 64 + lane) * 4) = outv;
    }
  }
}

// ---------------- unified LSTM recurrence ----------------
// MODE 0: enc-l0 (x-fused, Y out, 2 dirs)     grid 2*nbt*4
// MODE 2: enc-l1 (G input, 2 dirs)            grid 2*nbt*4
// MODE 1: FUSED decoder: blocks [0, nbt*4) = dec-l0 (x+zconst), blocks [nbt*4, nbt*12) =
//         dec-l1 (8-way col split, merged K=512 matmul vs [y0d;h1], out-projection).
//         l1 stages y0d directly from l0's exchange; l0 throttled by l1 flags.

struct RecArgs {
  const u16* Wr0; const u16* Wr1;       // Whh slabs (MODE1: Wr0=l0 Whh, Wr1=Wcat)
  int* flg0; int* flg1;                 // MODE1: flg0=l0(4/bt), flg1=l1(8/bt)
  u16* hX0; u16* hX1;                   // MODE1: hX0=l0 exch, hX1=l1 exch
  const u16* G0; const u16* G1; int btilesG;
  const float* x; const int* labels; const float* emb; int gb0;
  const float* cb0; const float* cb1;   // MODE0 bias per dir; MODE1: cb1 = db1 (l1 bias)
  const u16* Wx0; const u16* Wx1;
  const u16* zcF;
  const u16* hI0; const u16* hI1;       // MODE1: hI0=dh0, hI1=dh1
  const float* cI0; const float* cI1;   // MODE1: cI0=dc0, cI1=dc1
  float* cS0; float* cS1;
  u16* hW0; u16* hW1;
  u16* Y; int ycols; int yoff0; int yoff1;
  const u16* Wo; const float* bo; float* outp;
  int t0, t1, nbt;
};

template<int MODE>
__global__ __launch_bounds__(512, 1) void k_rec(RecArgs a){
  constexpr bool ENC0 = (MODE == 0);
  constexpr bool DEC  = (MODE == 1);
  constexpr bool GIN  = (MODE == 2);
  constexpr bool XIN  = (MODE <= 1);

  __shared__ __align__(16) char S[163840];
  u16* Wlds = (u16*)S;                 // 128 KB
  u16* hlds = (u16*)(S + 131072);      // 16 KB (l1 role: staged y0d)
  u16* hl1  = (u16*)(S + 147456);      // 16 KB (l1 role only)
  u16* xT   = (u16*)(S + 147456);      // 2 KB (l0/enc roles; overlaps hl1)

  const int bx = blockIdx.x;
  const int tid = threadIdx.x;
  const int lane = tid & 63, w = tid >> 6;
  const int l15 = lane & 15, lhi = lane >> 4;

  // =========================== role: fused dec-l1 ===========================
  if (DEC && bx >= a.nbt * 4){
    const int idx = bx - a.nbt * 4;
    const int ns8 = idx & 7;
    const int bt = idx >> 3;
    const int bb = bt * 32;
    const int mt = (w >> 1) & 1, ct = w & 1;
    const int colb = ns8 * 32 + ct * 16 + l15;
    const u16* Wsrc = a.Wr1 + (size_t)ns8 * 65536;
    int* ownflg = a.flg1 + bt * 8;
    const int* l0flg = a.flg0 + bt * 4;
    u16* hXo = a.hX1 + (size_t)bt * 16384;
    const u16* hXl0 = a.hX0 + (size_t)bt * 16384;

    // stage Wcat slab 128 KB
#pragma unroll
    for (int i = 0; i < 16; ++i){
      int ix = i * 512 + tid;
      *(f32x4_t*)((char*)Wlds + (size_t)ix * 16) = *(const f32x4_t*)((const char*)Wsrc + (size_t)ix * 16);
    }
    float cfr[4], bias4[4];
    if (w < 4){
#pragma unroll
      for (int g = 0; g < 4; ++g) bias4[g] = a.cb1[g * 256 + colb];
#pragma unroll
      for (int q = 0; q < 4; ++q)
        cfr[q] = a.cI1[(size_t)(bb + mt * 16 + lhi * 4 + q) * 256 + colb];
    }
    bf16x8_t wo8[8];
    float bo = 0.f;
    if (ns8 == 0 && (w == 4 || w == 5)){
#pragma unroll
      for (int ks = 0; ks < 8; ++ks)
        wo8[ks] = *(const bf16x8_t*)(a.Wo + (size_t)l15 * 256 + ks * 32 + lhi * 8);
      if (l15 < 12) bo = a.bo[l15];
    }
    unsigned dsA[8];
#pragma unroll
    for (int ks = 0; ks < 8; ++ks)
      dsA[ks] = (unsigned)((((mt * 16 + l15) << 5) + (((ks << 2) + lhi) ^ (l15 & 7))) * 16);
    unsigned wrO[4];
    if (w < 4){
#pragma unroll
      for (int q = 0; q < 4; ++q){
        int row = mt * 16 + lhi * 4 + q;
        wrO[q] = (unsigned)((row << 9) + (((colb >> 3) ^ (row & 7)) << 4) + ((colb & 7) << 1));
      }
      // publish h1(0)
#pragma unroll
      for (int q = 0; q < 4; ++q){
        u16 hv = a.hI1[(size_t)(bb + mt * 16 + lhi * 4 + q) * 256 + colb];
        st_u16_sc((char*)hXo + wrO[q], hv);
      }
    }
    __syncthreads();
    if (tid == 0) st_flag(ownflg + ns8, 1);

    auto spinL1 = [&](int tOwn, int tL0, int useL0){
      if (w == 0){
        while (true){
          int f = 0x7fffffff, tgt = 0;
          if (lane < 8){ f = ld_flag(ownflg + lane); tgt = tOwn; }
          else if (lane < 12 && useL0){ f = ld_flag((const int*)l0flg + (lane - 8)); tgt = tL0; }
          if (__all(f >= tgt)) break;
          __builtin_amdgcn_s_sleep(2);
        }
      }
      __syncthreads();
    };
    auto stage2 = [&](int parA, int parB, int doA){
      int o0 = w * 2048 + lane * 16;
      const char* sB = (const char*)hXo + parB * 16384;
      f32x4_t v0, v1, v2, v3;
      if (doA){
        const char* sA = (const char*)hXl0 + parA * 16384;
        ld4_b128_sc(sA + o0, sA + o0 + 1024, sB + o0, sB + o0 + 1024, &v0, &v1, &v2, &v3);
        *(f32x4_t*)((char*)hlds + o0) = v0;
        *(f32x4_t*)((char*)hlds + o0 + 1024) = v1;
      } else {
        ld2_b128_sc(sB + o0, sB + o0 + 1024, &v2, &v3);
      }
      *(f32x4_t*)((char*)hl1 + o0) = v2;
      *(f32x4_t*)((char*)hl1 + o0 + 1024) = v3;
    };

    spinL1(1, 2, 1);
    stage2(1, 0, 1);           // y0d[0] = h_l0(1) parity 1; h1(0) parity 0
    __syncthreads();

    for (int t = 0; t < TT; ++t){
      // out-projection of h1(t) -> out[t-1]  (waves 4-5, ns8==0)
      if (ns8 == 0 && (w == 4 || w == 5) && t > 0){
        f32x4_t oa = (f32x4_t){0.f, 0.f, 0.f, 0.f};
#pragma unroll
        for (int ks = 0; ks < 8; ++ks){
          bf16x8_t af = *(const bf16x8_t*)((char*)hl1 + (w - 4) * 8192 + dsA[ks]);
          oa = MFMA(af, wo8[ks], oa);
        }
        if (l15 < 12){
#pragma unroll
          for (int q = 0; q < 4; ++q)
            a.outp[((size_t)(bb + (w - 4) * 16 + lhi * 4 + q) * TT + (t - 1)) * 12 + l15] = oa[q] + bo;
        }
      }
      const int par = (t + 1) & 1;
      if (w < 4){
        f32x4_t acc[4];
#pragma unroll
        for (int g = 0; g < 4; ++g) acc[g] = (f32x4_t){bias4[g], bias4[g], bias4[g], bias4[g]};
#pragma unroll
        for (int ks = 0; ks < 16; ++ks){
          bf16x8_t af = (ks < 8)
            ? *(const bf16x8_t*)((char*)hlds + dsA[ks])
            : *(const bf16x8_t*)((char*)hl1 + dsA[ks - 8]);
#pragma unroll
          for (int g = 0; g < 4; ++g){
            bf16x8_t bf = *(const bf16x8_t*)((char*)Wlds + ((g * 2 + ct) * 16 + ks) * 1024 + lane * 16);
            acc[g] = MFMA(af, bf, acc[g]);
          }
        }
#pragma unroll
        for (int q = 0; q < 4; ++q){
          float iv = sigm(acc[0][q]);
          float fv = sigm(acc[1][q]);
          float gv = tanh_(acc[2][q]);
          float ov = sigm(acc[3][q]);
          float c = fv * cfr[q] + iv * gv;
          cfr[q] = c;
          st_u16_sc((char*)hXo + par * 16384 + wrO[q], f2bf(ov * tanh_(c)));
        }
      }
      __syncthreads();
      if (tid == 0) st_flag(ownflg + ns8, t + 2);
      int more = (t + 1 < TT);
      spinL1(t + 2, t + 3, more);
      stage2(t & 1, par, more);
      __syncthreads();
    }
    // epilogue: h1(TT) -> out[TT-1]
    if (ns8 == 0 && (w == 4 || w == 5)){
      f32x4_t oa = (f32x4_t){0.f, 0.f, 0.f, 0.f};
#pragma unroll
      for (int ks = 0; ks < 8; ++ks){
        bf16x8_t af = *(const bf16x8_t*)((char*)hl1 + (w - 4) * 8192 + dsA[ks]);
        oa = MFMA(af, wo8[ks], oa);
      }
      if (l15 < 12){
#pragma unroll
        for (int q = 0; q < 4; ++q)
          a.outp[((size_t)(bb + (w - 4) * 16 + lhi * 4 + q) * TT + (TT - 1)) * 12 + l15] = oa[q] + bo;
      }
    }
    return;
  }

  // =========================== roles: enc-l0 / enc-l1 / dec-l0 ===========================
  const int ns = bx & 3;
  const int gid = bx >> 2;
  const int dir = DEC ? 0 : (gid / a.nbt);
  const int bt = DEC ? gid : (gid - dir * a.nbt);
  const int bb = bt * 32;
  const int mt = w >> 2, ct = w & 3;
  const int colb = ns * 64 + ct * 16 + l15;

  const u16* Wsrc = (dir ? a.Wr1 : a.Wr0) + (size_t)ns * 65536;
  int* flg = (dir ? a.flg1 : a.flg0) + bt * 4;
  const int* l1flg = DEC ? (a.flg1 + bt * 8) : nullptr;
  u16* hXg = (dir ? a.hX1 : a.hX0) + (size_t)bt * 16384;
  const int yoff = dir ? a.yoff1 : a.yoff0;

#pragma unroll
  for (int i = 0; i < 16; ++i){
    int ix = i * 512 + tid;
    *(f32x4_t*)((char*)Wlds + (size_t)ix * 16) = *(const f32x4_t*)((const char*)Wsrc + (size_t)ix * 16);
  }

  float cfr[4];
  {
    const float* cp = dir ? a.cI1 : a.cI0;
#pragma unroll
    for (int q = 0; q < 4; ++q)
      cfr[q] = cp ? cp[(size_t)(bb + mt * 16 + lhi * 4 + q) * 256 + colb] : 0.f;
  }

  float bias4[4];
  f32x4_t zcv[4];
  bf16x8_t wfx[4];
  if (ENC0){
    const float* cb = dir ? a.cb1 : a.cb0;
#pragma unroll
    for (int g = 0; g < 4; ++g) bias4[g] = cb[g * 256 + colb];
  }
  if (DEC){
#pragma unroll
    for (int g = 0; g < 4; ++g){
      int ntile = g * 16 + ns * 4 + ct;
      bf16x4_t zv = *(const bf16x4_t*)(a.zcF + ((((size_t)((bb >> 4) + mt)) * 64 + ntile) * 64 + lane) * 4);
      zcv[g] = cvt4(zv);
    }
  }
  if (XIN){
    const u16* Wx = dir ? a.Wx1 : a.Wx0;
#pragma unroll
    for (int g = 0; g < 4; ++g)
      wfx[g] = *(const bf16x8_t*)(Wx + (size_t)(g * 256 + colb) * 32 + lhi * 8);
  }

  if (XIN){
    int row = tid >> 4, c16 = tid & 15;
    int gr = a.gb0 + bb + row;
    u16 vA = 0, vB = 0;
    if (!DEC){
      int lb = a.labels[gr];
      if (c16 >= 12) vA = f2bf(a.emb[lb * 8 + (c16 - 12)]);
      if (c16 < 4)   vB = f2bf(a.emb[lb * 8 + 4 + c16]);
    }
    u16 x0 = 0;
    if (!DEC && c16 < 12){
      int t0src = dir ? (TT - 1) : 0;
      x0 = f2bf(a.x[((size_t)gr * TT + t0src) * 12 + c16]);
    }
    xT[row * 32 + c16] = (c16 < 12) ? x0 : vA;
    xT[row * 32 + 16 + c16] = vB;
  }

  unsigned dsA[8];
#pragma unroll
  for (int ks = 0; ks < 8; ++ks)
    dsA[ks] = (unsigned)((((mt * 16 + l15) << 5) + (((ks << 2) + lhi) ^ (l15 & 7))) * 16);
  unsigned wrO[4];
#pragma unroll
  for (int q = 0; q < 4; ++q){
    int row = mt * 16 + lhi * 4 + q;
    wrO[q] = (unsigned)((row << 9) + (((colb >> 3) ^ (row & 7)) << 4) + ((colb & 7) << 1));
  }
  const char* Gc = GIN ? (const char*)(dir ? a.G1 : a.G0) : nullptr;
  unsigned gOff[4];
  const unsigned gstep = (unsigned)a.btilesG * 32768u;
  bf16x4_t gvP[4];
  if (GIN){
#pragma unroll
    for (int g = 0; g < 4; ++g){
      int ntile = g * 16 + ns * 4 + ct;
      gOff[g] = (unsigned)((((bb >> 4) + mt) * 64 + ntile) * 512 + lane * 8);
    }
#pragma unroll
    for (int g = 0; g < 4; ++g)
      gvP[g] = *(const bf16x4_t*)(Gc + gOff[g]);
  }

  if (a.t0 == 0){
    const u16* hp = dir ? a.hI1 : a.hI0;
    const u16* hq = DEC ? a.hI0 : hp;
#pragma unroll
    for (int q = 0; q < 4; ++q){
      u16 hv = hq ? hq[(size_t)(bb + mt * 16 + lhi * 4 + q) * 256 + colb] : (u16)0;
      st_u16_sc((char*)hXg + wrO[q], hv);
    }
  }
  __syncthreads();
  if (tid == 0 && a.t0 == 0) st_flag(flg + ns, 1);

  auto spin_to = [&](int tOwn, int tL1){
    if (w == 0){
      while (true){
        int f = 0x7fffffff, tgt = 0;
        if (lane < 4){ f = ld_flag(flg + lane); tgt = tOwn; }
        else if (DEC && lane < 12){ f = ld_flag((const int*)l1flg + (lane - 4)); tgt = tL1; }
        if (__all(f >= tgt)) break;
        __builtin_amdgcn_s_sleep(2);
      }
    }
    __syncthreads();
  };
  auto stage_h = [&](int par){
    const char* src = (const char*)hXg + par * 16384;
    int o0 = w * 2048 + lane * 16;
    f32x4_t v0, v1;
    ld2_b128_sc(src + o0, src + o0 + 1024, &v0, &v1);
    *(f32x4_t*)((char*)hlds + o0) = v0;
    *(f32x4_t*)((char*)hlds + o0 + 1024) = v1;
  };

  spin_to(a.t0 + 1, 0);
  stage_h(a.t0 & 1);
  __syncthreads();

  for (int t = a.t0; t < a.t1; ++t){
    f32x4_t acc[4];
    if (GIN){
#pragma unroll
      for (int g = 0; g < 4; ++g) acc[g] = cvt4(gvP[g]);
    } else if (DEC){
#pragma unroll
      for (int g = 0; g < 4; ++g) acc[g] = zcv[g];
    } else {
#pragma unroll
      for (int g = 0; g < 4; ++g) acc[g] = (f32x4_t){bias4[g], bias4[g], bias4[g], bias4[g]};
    }
    if (XIN){
      bf16x8_t ax = *(const bf16x8_t*)((char*)xT + (mt * 16 + l15) * 64 + lhi * 16);
#pragma unroll
      for (int g = 0; g < 4; ++g) acc[g] = MFMA(ax, wfx[g], acc[g]);
    }
#pragma unroll
    for (int ks = 0; ks < 8; ++ks){
      bf16x8_t af = *(const bf16x8_t*)((char*)hlds + dsA[ks]);
#pragma unroll
      for (int g = 0; g < 4; ++g){
        bf16x8_t bf = *(const bf16x8_t*)((char*)Wlds + ((g * 4 + ct) * 8 + ks) * 1024 + lane * 16);
        acc[g] = MFMA(af, bf, acc[g]);
      }
    }
    const int par = (t + 1) & 1;
    u16 hbv[4];
#pragma unroll
    for (int q = 0; q < 4; ++q){
      float iv = sigm(acc[0][q]);
      float fv = sigm(acc[1][q]);
      float gv = tanh_(acc[2][q]);
      float ov = sigm(acc[3][q]);
      float c = fv * cfr[q] + iv * gv;
      cfr[q] = c;
      u16 hb = f2bf(ov * tanh_(c));
      hbv[q] = hb;
      st_u16_sc((char*)hXg + par * 16384 + wrO[q], hb);
    }
    __syncthreads();
    if (tid == 0) st_flag(flg + ns, t + 2);
    if (ENC0){
      const int ty = dir ? (TT - 1 - t) : t;
#pragma unroll
      for (int q = 0; q < 4; ++q)
        a.Y[((size_t)(bb + mt * 16 + lhi * 4 + q) * TT + ty) * a.ycols + yoff + colb] = hbv[q];
    }
    if (GIN){
#pragma unroll
      for (int g = 0; g < 4; ++g) gOff[g] += gstep;
      if (t + 1 < a.t1){
#pragma unroll
        for (int g = 0; g < 4; ++g)
          gvP[g] = *(const bf16x4_t*)(Gc + gOff[g]);
      }
    }
    spin_to(t + 2, t + 1);
    stage_h(par);
    if (XIN && (t + 1) < a.t1){
      if (tid < 128 && (tid & 3) < 3){
        int row = tid >> 2, xq = tid & 3;
        int tsrc = DEC ? t : (dir ? (TT - 2 - t) : (t + 1));
        f32x4_t xv = *(const f32x4_t*)(a.x + ((size_t)(a.gb0 + bb + row) * TT + tsrc) * 12 + xq * 4);
        bf16x4_t xb;
#pragma unroll
        for (int e = 0; e < 4; ++e) xb[e] = (short)f2bf(xv[e]);
        *(bf16x4_t*)((char*)xT + row * 64 + xq * 8) = xb;
      }
    }
    __syncthreads();
  }

  {
    float* cs = dir ? a.cS1 : a.cS0;
    if (cs){
#pragma unroll
      for (int q = 0; q < 4; ++q)
        cs[(size_t)(bb + mt * 16 + lhi * 4 + q) * 256 + colb] = cfr[q];
    }
    u16* hw = dir ? a.hW1 : a.hW0;
    if (hw){
#pragma unroll
      for (int q = 0; q < 4; ++q){
        u16 hv = *(u16*)((char*)hlds + wrO[q]);
        hw[(size_t)(bb + mt * 16 + lhi * 4 + q) * 256 + colb] = hv;
      }
    }
  }
}

// ---------------- mid kernels ----------------

__global__ void k_mulv(const u16* sH0, const u16* sH1,
                       const float* Wmu, const float* bmu,
                       const float* Wlv, const float* blv, float* mulv){
  int i = blockIdx.x * blockDim.x + threadIdx.x;
  if (i >= BFULL * 128) return;
  int b = i >> 7, j = i & 127;
  const float* W = (j < 64) ? (Wmu + (size_t)j * 512) : (Wlv + (size_t)(j - 64) * 512);
  float s = (j < 64) ? bmu[j] : blv[j - 64];
  for (int k = 0; k < 256; ++k) s += bf2f(sH0[(size_t)b * 256 + k]) * W[k];
  for (int k = 0; k < 256; ++k) s += bf2f(sH1[(size_t)b * 256 + k]) * W[256 + k];
  mulv[i] = s;
}

__global__ void k_sample(const float* mulv, const float* eps, const int* labels, const float* emb,
                         float* out_mu, float* out_lv, float* out_z, float* zcf){
  int i = blockIdx.x * blockDim.x + threadIdx.x;
  if (i >= BFULL * 128) return;
  int b = i >> 7, j = i & 127;
  if (j < 64){
    float mu = mulv[b * 128 + j];
    float lv = mulv[b * 128 + 64 + j];
    float z = mu + eps[b * 64 + j] * __expf(0.5f * lv);
    out_mu[b * 64 + j] = mu;
    out_lv[b * 64 + j] = lv;
    out_z[b * 64 + j] = z;
    zcf[i] = z;
  } else if (j < 72){
    zcf[i] = emb[labels[b] * 8 + (j - 64)];
  } else {
    zcf[i] = 0.f;
  }
}

__global__ void k_hc(const float* zcf, const float* Whid, const float* bhid,
                     const float* Wcell, const float* bcell, float* HC){
  int i = blockIdx.x * blockDim.x + threadIdx.x;
  if (i >= BFULL * 1024) return;
  int b = i >> 10, n = i & 1023;
  const float* W; float s;
  if (n < 512){ W = Whid + (size_t)n * 72; s = bhid[n]; }
  else        { W = Wcell + (size_t)(n - 512) * 72; s = bcell[n - 512]; }
  for (int k = 0; k < 72; ++k) s += zcf[b * 128 + k] * W[k];
  HC[i] = s;
}

__global__ void k_zconst(const float* zcf, const float* dWih0,
                         const float* dbih0, const float* dbhh0, float* zconst){
  int i = blockIdx.x * blockDim.x + threadIdx.x;
  if (i >= BFULL * 1024) return;
  int b = i >> 10, n = i & 1023;
  float s = dbih0[n] + dbhh0[n];
  const float* W = dWih0 + (size_t)n * 84 + 12;
  for (int k = 0; k < 72; ++k) s += zcf[b * 128 + k] * W[k];
  zconst[i] = s;
}

__global__ void k_zfrag(const float* zconst, u16* zcF){
  int i = blockIdx.x * blockDim.x + threadIdx.x;
  if (i >= BFULL * GH) return;
  int q = i & 3, ln = (i >> 2) & 63, nt = (i >> 8) & 63, bt = i >> 14;
  int r = bt * 16 + (ln >> 4) * 4 + q;
  int col = nt * 16 + (ln & 15);
  zcF[i] = f2bf(zconst[(size_t)r * GH + col]);
}

// faithful torch .view(NL, B, H) on [B, NL*H]
__global__ void k_dec_init(const float* HC, u16* h0, float* c0, u16* h1, float* c1){
  int i = blockIdx.x * blockDim.x + threadIdx.x;
  if (i >= BFULL * 256) return;
  int b = i >> 8, h = i & 255;
  int col = (b & 1) * 256 + h;
  int r0 = b >> 1;
  int r1 = 256 + (b >> 1);
  h0[i] = f2bf(HC[(size_t)r0 * 1024 + col]);
  c0[i] =      HC[(size_t)r0 * 1024 + 512 + col];
  h1[i] = f2bf(HC[(size_t)r1 * 1024 + col]);
  c1[i] =      HC[(size_t)r1 * 1024 + 512 + col];
}

// ---------------- host ----------------

static inline size_t alignup(size_t x){ return (x + 255) & ~(size_t)255; }
static inline int ilog2(int x){ return 31 - __builtin_clz((unsigned)x); }

extern "C" void kernel_launch(void* const* d_in, const int* in_sizes, int n_in,
                              void* d_out, int out_size, void* d_ws, size_t ws_size,
                              hipStream_t stream){
  const float* x      = (const float*)d_in[0];
  const int*   labels = (const int*)  d_in[1];
  const float* eps    = (const float*)d_in[2];
  const float* emb    = (const float*)d_in[3];
  const float* Wih0f = (const float*)d_in[4],  *Whh0f = (const float*)d_in[5];
  const float* bih0f = (const float*)d_in[6],  *bhh0f = (const float*)d_in[7];
  const float* Wih0b = (const float*)d_in[8],  *Whh0b = (const float*)d_in[9];
  const float* bih0b = (const float*)d_in[10], *bhh0b = (const float*)d_in[11];
  const float* Wih1f = (const float*)d_in[12], *Whh1f = (const float*)d_in[13];
  const float* bih1f = (const float*)d_in[14], *bhh1f = (const float*)d_in[15];
  const float* Wih1b = (const float*)d_in[16], *Whh1b = (const float*)d_in[17];
  const float* bih1b = (const float*)d_in[18], *bhh1b = (const float*)d_in[19];
  const float* Wmu = (const float*)d_in[20], *bmu = (const float*)d_in[21];
  const float* Wlv = (const float*)d_in[22], *blv = (const float*)d_in[23];
  const float* Whid = (const float*)d_in[24], *bhid = (const float*)d_in[25];
  const float* Wcell = (const float*)d_in[26], *bcell = (const float*)d_in[27];
  const float* dWih0 = (const float*)d_in[28], *dWhh0 = (const float*)d_in[29];
  const float* dbih0 = (const float*)d_in[30], *dbhh0 = (const float*)d_in[31];
  const float* dWih1 = (const float*)d_in[32], *dWhh1 = (const float*)d_in[33];
  const float* dbih1 = (const float*)d_in[34], *dbhh1 = (const float*)d_in[35];
  const float* Wout = (const float*)d_in[36], *bout = (const float*)d_in[37];

  float* out = (float*)d_out;
  float* out_mu = out + (size_t)BFULL * TT * 12;
  float* out_lv = out_mu + (size_t)BFULL * 64;
  float* out_z  = out_lv + (size_t)BFULL * 64;

  char* ws = (char*)d_ws; size_t off = 0;
  auto alloc = [&](size_t bytes)->char*{ char* p = ws + off; off += alignup(bytes); return p; };

  u16* W0f_b  = (u16*)alloc(1024 * 32 * 2);
  u16* W0b_b  = (u16*)alloc(1024 * 32 * 2);
  u16* dWx_b  = (u16*)alloc(1024 * 32 * 2);
  u16* Wo_b   = (u16*)alloc(16 * 256 * 2);
  u16* Whh0f_r = (u16*)alloc((size_t)1024 * 256 * 2);
  u16* Whh0b_r = (u16*)alloc((size_t)1024 * 256 * 2);
  u16* Whh1f_r = (u16*)alloc((size_t)1024 * 256 * 2);
  u16* Whh1b_r = (u16*)alloc((size_t)1024 * 256 * 2);
  u16* dWhh0_r = (u16*)alloc((size_t)1024 * 256 * 2);
  u16* Wcat_r  = (u16*)alloc((size_t)1024 * 512 * 2);
  u16* Wih1f_b = (u16*)alloc((size_t)1024 * 512 * 2);
  u16* Wih1b_b = (u16*)alloc((size_t)1024 * 512 * 2);
  float* b0f = (float*)alloc(1024 * 4);
  float* b0b = (float*)alloc(1024 * 4);
  float* b1f = (float*)alloc(1024 * 4);
  float* b1b = (float*)alloc(1024 * 4);
  float* db1 = (float*)alloc(1024 * 4);
  u16*  sHe1 = (u16*)alloc((size_t)2 * BFULL * 256 * 2);
  float* sCe1 = (float*)alloc((size_t)2 * BFULL * 256 * 4);
  u16*  dh0 = (u16*)alloc((size_t)BFULL * 256 * 2);
  float* dc0 = (float*)alloc((size_t)BFULL * 256 * 4);
  u16*  dh1 = (u16*)alloc((size_t)BFULL * 256 * 2);
  float* dc1 = (float*)alloc((size_t)BFULL * 256 * 4);
  float* mulv = (float*)alloc((size_t)BFULL * 128 * 4);
  float* zcf  = (float*)alloc((size_t)BFULL * 128 * 4);
  float* HC   = (float*)alloc((size_t)BFULL * 1024 * 4);
  float* zconst = (float*)alloc((size_t)BFULL * 1024 * 4);
  u16*  zcF   = (u16*)alloc((size_t)BFULL * 1024 * 2);
  int*  flagsA = (int*)alloc(768 * 4);                         // [layer][dir][bt][ns] + l1 flags
  int*  flagsB = flagsA + 512;                                 // [bt16][ns8]
  u16*  hXA    = (u16*)alloc((size_t)2 * 16 * 16384 * 2);      // [slot2][bt16][2par][8192]

  size_t rem = (ws_size > off + (1 << 20)) ? ws_size - off - (1 << 20) : 0;
  int eb = 128, Tc = 2;
  {
    const int sch[][2] = {
      {512,360},{512,120},{512,40},{512,24},{512,12},{512,8},
      {256,360},{256,120},{256,40},{256,12},{256,8},
      {128,360},{128,40},{128,8},{128,2}};
    for (int i = 0; i < (int)(sizeof(sch)/sizeof(sch[0])); ++i){
      size_t need = alignup((size_t)sch[i][0] * TT * 512 * 2)
                  + 2 * alignup((size_t)sch[i][1] * sch[i][0] * GH * 2);
      if (need <= rem){ eb = sch[i][0]; Tc = sch[i][1]; break; }
    }
  }
  const int ebLog = ilog2(eb);
  const int nGroups = BFULL / eb;
  const int nbt = eb / 32;

  u16* y0 = (u16*)alloc((size_t)eb * TT * 512 * 2);
  u16* Gf = (u16*)alloc((size_t)Tc * eb * GH * 2);
  u16* Gb = (u16*)alloc((size_t)Tc * eb * GH * 2);

  auto cvt = [&](const float* src, u16* dst, int N, int srcK, int useK, int Np, int Kp){
    int tot = Np * Kp;
    k_cvt_pad<<<(tot + 255) / 256, 256, 0, stream>>>(src, dst, N, srcK, useK, Np, Kp);
  };
  auto repack = [&](const float* src, u16* dst){
    k_repack<<<1024, 256, 0, stream>>>(src, dst);
  };
  auto bsum = [&](const float* a, const float* b, float* o){
    k_bias_sum<<<4, 256, 0, stream>>>(a, b, o, 1024);
  };
  auto proj = [&](const u16* A, int Akp, int K, const u16* W, const float* cbp,
                  u16* G, int t0, int tc, int rev){
    ProjArgs pa; pa.A = A; pa.W = W; pa.colbias = cbp; pa.G = G;
    pa.Akp = Akp; pa.K = K; pa.t0 = t0; pa.rev = rev; pa.Bg = eb; pa.bgLog = ebLog;
    dim3 grid(tc * (eb / 128), 8);
    k_proj<64><<<grid, 256, 0, stream>>>(pa);
  };
  auto flgbase = [&](int layer, int d, int gb0){ return flagsA + ((layer * 2 + d) * 16 + (gb0 >> 5)) * 4; };
  auto hxbase  = [&](int d, int gb0){ return hXA + ((size_t)d * 16 + (gb0 >> 5)) * 16384; };

  k_zero<<<3, 256, 0, stream>>>(flagsA, 768);
  cvt(Wih0f, W0f_b, 1024, 20, 20, 1024, 32);
  cvt(Wih0b, W0b_b, 1024, 20, 20, 1024, 32);
  cvt(dWih0, dWx_b, 1024, 84, 12, 1024, 32);
  cvt(Wout,  Wo_b,  12, 256, 256, 16, 256);
  repack(Whh0f, Whh0f_r);
  repack(Whh0b, Whh0b_r);
  repack(Whh1f, Whh1f_r);
  repack(Whh1b, Whh1b_r);
  repack(dWhh0, dWhh0_r);
  k_repack_cat<<<2048, 256, 0, stream>>>(dWih1, dWhh1, Wcat_r);
  cvt(Wih1f, Wih1f_b, 1024, 512, 512, 1024, 512);
  cvt(Wih1b, Wih1b_b, 1024, 512, 512, 1024, 512);
  bsum(bih0f, bhh0f, b0f);
  bsum(bih0b, bhh0b, b0b);
  bsum(bih1f, bhh1f, b1f);
  bsum(bih1b, bhh1b, b1b);
  bsum(dbih1, dbhh1, db1);

  // ---- encoder ----
  for (int g = 0; g < nGroups; ++g){
    int gb0 = g * eb;
    {
      RecArgs ra = {};
      ra.Wr0 = Whh0f_r; ra.Wr1 = Whh0b_r;
      ra.flg0 = flgbase(0, 0, gb0); ra.flg1 = flgbase(0, 1, gb0);
      ra.hX0 = hxbase(0, gb0); ra.hX1 = hxbase(1, gb0);
      ra.x = x; ra.labels = labels; ra.emb = emb; ra.gb0 = gb0;
      ra.cb0 = b0f; ra.cb1 = b0b;
      ra.Wx0 = W0f_b; ra.Wx1 = W0b_b;
      ra.Y = y0; ra.ycols = 512; ra.yoff0 = 0; ra.yoff1 = 256;
      ra.t0 = 0; ra.t1 = TT; ra.nbt = nbt;
      k_rec<0><<<2 * nbt * 4, 512, 0, stream>>>(ra);
    }
    for (int t0 = 0; t0 < TT; t0 += Tc){
      int t1 = (t0 + Tc < TT) ? t0 + Tc : TT; int tc = t1 - t0;
      proj(y0, 512, 512, Wih1f_b, b1f, Gf, t0, tc, 0);
      proj(y0, 512, 512, Wih1b_b, b1b, Gb, t0, tc, 1);
      RecArgs ra = {};
      ra.Wr0 = Whh1f_r; ra.Wr1 = Whh1b_r;
      ra.flg0 = flgbase(1, 0, gb0); ra.flg1 = flgbase(1, 1, gb0);
      ra.hX0 = hxbase(0, gb0); ra.hX1 = hxbase(1, gb0);
      ra.G0 = Gf; ra.G1 = Gb; ra.btilesG = eb >> 4;
      ra.cI0 = t0 ? (sCe1 + (size_t)gb0 * 256) : nullptr;
      ra.cI1 = t0 ? (sCe1 + (size_t)BFULL * 256 + (size_t)gb0 * 256) : nullptr;
      ra.cS0 = sCe1 + (size_t)gb0 * 256;
      ra.cS1 = sCe1 + (size_t)BFULL * 256 + (size_t)gb0 * 256;
      ra.hW0 = sHe1 + (size_t)gb0 * 256;
      ra.hW1 = sHe1 + (size_t)BFULL * 256 + (size_t)gb0 * 256;
      ra.t0 = t0; ra.t1 = t1; ra.nbt = nbt;
      k_rec<2><<<2 * nbt * 4, 512, 0, stream>>>(ra);
    }
  }

  // ---- VAE head + decoder init ----
  k_mulv<<<(BFULL * 128) / 256, 256, 0, stream>>>(sHe1, sHe1 + (size_t)BFULL * 256,
                                                  Wmu, bmu, Wlv, blv, mulv);
  k_sample<<<(BFULL * 128) / 256, 256, 0, stream>>>(mulv, eps, labels, emb,
                                                    out_mu, out_lv, out_z, zcf);
  k_hc<<<(BFULL * 1024) / 256, 256, 0, stream>>>(zcf, Whid, bhid, Wcell, bcell, HC);
  k_zconst<<<(BFULL * 1024) / 256, 256, 0, stream>>>(zcf, dWih0, dbih0, dbhh0, zconst);
  k_zfrag<<<(BFULL * GH) / 256, 256, 0, stream>>>(zconst, zcF);
  k_dec_init<<<(BFULL * 256) / 256, 256, 0, stream>>>(HC, dh0, dc0, dh1, dc1);

  // ---- decoder (fused l0+l1 pipeline) ----
  for (int g = 0; g < nGroups; ++g){
    int gb0 = g * eb;
    RecArgs ra = {};
    ra.Wr0 = dWhh0_r; ra.Wr1 = Wcat_r;
    ra.flg0 = flgbase(2, 0, gb0); ra.flg1 = flagsB + (gb0 >> 5) * 8;
    ra.hX0 = hxbase(0, gb0); ra.hX1 = hxbase(1, gb0);
    ra.x = x; ra.gb0 = gb0;
    ra.zcF = zcF + ((size_t)(gb0 >> 4)) * 16384;
    ra.Wx0 = dWx_b; ra.Wx1 = dWx_b;
    ra.hI0 = dh0 + (size_t)gb0 * 256;
    ra.cI0 = dc0 + (size_t)gb0 * 256;
    ra.hI1 = dh1 + (size_t)gb0 * 256;
    ra.cI1 = dc1 + (size_t)gb0 * 256;
    ra.cb1 = db1;
    ra.Wo = Wo_b; ra.bo = bout;
    ra.outp = out + (size_t)gb0 * TT * 12;
    ra.t0 = 0; ra.t1 = TT; ra.nbt = nbt;
    k_rec<1><<<nbt * 12, 512, 0, stream>>>(ra);
  }
}